// Round 1
// baseline (2939.288 us; speedup 1.0000x reference)
//
#include <hip/hip_runtime.h>
#include <hip/hip_bf16.h>

// -------------------- small helpers --------------------
static inline size_t ws_align(size_t x) { return (x + 255) & ~(size_t)255; }

// -------------------- degree / norm --------------------
__global__ void k_deg_init(float* __restrict__ deg, int n) {
    int i = blockIdx.x * blockDim.x + threadIdx.x;
    if (i < n) deg[i] = 1.0f;  // self-loop contributes 1
}

__global__ void k_deg_acc(const int* __restrict__ dst, float* __restrict__ deg, int E) {
    int e = blockIdx.x * blockDim.x + threadIdx.x;
    if (e < E) atomicAdd(&deg[dst[e]], 1.0f);
}

__global__ void k_rsqrt(float* __restrict__ deg, int n) {
    int i = blockIdx.x * blockDim.x + threadIdx.x;
    if (i < n) deg[i] = rsqrtf(deg[i]);
}

// -------------------- self-loop init: out[i][:] = feat[i][:] * dinv[i]^2 --------------------
// one float4 per thread; n32 = N*32 (128 floats per row = 32 float4)
__global__ void k_self_init(const float* __restrict__ feat, const float* __restrict__ dinv,
                            float* __restrict__ out, int n32) {
    int idx = blockIdx.x * blockDim.x + threadIdx.x;
    if (idx >= n32) return;
    int i = idx >> 5;
    float w = dinv[i] * dinv[i];
    float4 v = ((const float4*)feat)[idx];
    ((float4*)out)[idx] = make_float4(v.x * w, v.y * w, v.z * w, v.w * w);
}

// -------------------- edge scatter: out[dst] += feat[src] * dinv[src]*dinv[dst] --------------------
// 64 lanes per edge, float2 (8B) per lane -> 512B coalesced gather per edge.
__global__ void k_scatter(const float* __restrict__ feat, float* __restrict__ out,
                          const int* __restrict__ src, const int* __restrict__ dst,
                          const float* __restrict__ dinv, int E) {
    int e = (blockIdx.x << 2) + (threadIdx.x >> 6);
    if (e >= E) return;
    int lane = threadIdx.x & 63;
    int s = src[e], d = dst[e];
    float w = dinv[s] * dinv[d];
    const float2 v = *(const float2*)(feat + (size_t)s * 128 + lane * 2);
    float* p = out + (size_t)d * 128 + lane * 2;
    atomicAdd(p,     v.x * w);
    atomicAdd(p + 1, v.y * w);
}

// -------------------- GEMM1: F = relu(F @ W + b), in-place, W is 128x128 --------------------
// Block: 256 threads = 16 ty (4 rows each) x 16 tx (8 cols each); tile = 64 rows x 128 cols.
// W staged fully in LDS (64 KB). F rows read via L1 (working set 32KB/tile), written back
// after the full k-loop; rows are private to one 16-lane group of one wave -> in-place safe.
__global__ __launch_bounds__(256) void k_gemm_relu_inplace(
        float* __restrict__ F, const float* __restrict__ W,
        const float* __restrict__ b, int nrows) {
    __shared__ float Ws[128 * 128];
    for (int t = threadIdx.x; t < 128 * 128 / 4; t += 256)
        ((float4*)Ws)[t] = ((const float4*)W)[t];
    __syncthreads();

    const int ty = threadIdx.x >> 4, tx = threadIdx.x & 15;
    const int r0 = blockIdx.x * 64 + ty * 4;
    const int c0 = tx * 8;

    float acc[4][8];
#pragma unroll
    for (int i = 0; i < 4; i++)
#pragma unroll
        for (int j = 0; j < 8; j++) acc[i][j] = 0.0f;

    for (int kb = 0; kb < 128; kb += 4) {
        float fk[4][4];
#pragma unroll
        for (int i = 0; i < 4; i++) {
            int r = r0 + i;
            float4 a = (r < nrows) ? *(const float4*)(F + (size_t)r * 128 + kb)
                                   : make_float4(0.f, 0.f, 0.f, 0.f);
            fk[i][0] = a.x; fk[i][1] = a.y; fk[i][2] = a.z; fk[i][3] = a.w;
        }
#pragma unroll
        for (int kk = 0; kk < 4; kk++) {
            const float4 w0 = *(const float4*)(Ws + (kb + kk) * 128 + c0);
            const float4 w1 = *(const float4*)(Ws + (kb + kk) * 128 + c0 + 4);
            const float wv[8] = {w0.x, w0.y, w0.z, w0.w, w1.x, w1.y, w1.z, w1.w};
#pragma unroll
            for (int i = 0; i < 4; i++) {
                const float f = fk[i][kk];
#pragma unroll
                for (int j = 0; j < 8; j++) acc[i][j] = fmaf(f, wv[j], acc[i][j]);
            }
        }
    }

    const float4 b0 = *(const float4*)(b + c0);
    const float4 b1v = *(const float4*)(b + c0 + 4);
#pragma unroll
    for (int i = 0; i < 4; i++) {
        int r = r0 + i;
        if (r >= nrows) continue;
        float4 o0 = make_float4(fmaxf(acc[i][0] + b0.x, 0.f), fmaxf(acc[i][1] + b0.y, 0.f),
                                fmaxf(acc[i][2] + b0.z, 0.f), fmaxf(acc[i][3] + b0.w, 0.f));
        float4 o1 = make_float4(fmaxf(acc[i][4] + b1v.x, 0.f), fmaxf(acc[i][5] + b1v.y, 0.f),
                                fmaxf(acc[i][6] + b1v.z, 0.f), fmaxf(acc[i][7] + b1v.w, 0.f));
        *(float4*)(F + (size_t)r * 128 + c0) = o0;
        *(float4*)(F + (size_t)r * 128 + c0 + 4) = o1;
    }
}

// -------------------- GEMM2: out = G @ [Wmu | Wlv] + [bmu | blv], split-write to d_out --------------------
__global__ __launch_bounds__(256) void k_gemm_out(
        const float* __restrict__ G,
        const float* __restrict__ Wmu, const float* __restrict__ Wlv,
        const float* __restrict__ bmu, const float* __restrict__ blv,
        float* __restrict__ out, int nrows) {
    __shared__ float Ws[128 * 128];
    for (int t = threadIdx.x; t < 128 * 16; t += 256) {  // 2048 iterations of float4
        int k = t >> 4, jq = t & 15;
        ((float4*)(Ws + k * 128))[jq]      = ((const float4*)(Wmu + k * 64))[jq];
        ((float4*)(Ws + k * 128 + 64))[jq] = ((const float4*)(Wlv + k * 64))[jq];
    }
    __syncthreads();

    const int ty = threadIdx.x >> 4, tx = threadIdx.x & 15;
    const int r0 = blockIdx.x * 64 + ty * 4;
    const int c0 = tx * 8;

    float acc[4][8];
#pragma unroll
    for (int i = 0; i < 4; i++)
#pragma unroll
        for (int j = 0; j < 8; j++) acc[i][j] = 0.0f;

    for (int kb = 0; kb < 128; kb += 4) {
        float fk[4][4];
#pragma unroll
        for (int i = 0; i < 4; i++) {
            int r = r0 + i;
            float4 a = (r < nrows) ? *(const float4*)(G + (size_t)r * 128 + kb)
                                   : make_float4(0.f, 0.f, 0.f, 0.f);
            fk[i][0] = a.x; fk[i][1] = a.y; fk[i][2] = a.z; fk[i][3] = a.w;
        }
#pragma unroll
        for (int kk = 0; kk < 4; kk++) {
            const float4 w0 = *(const float4*)(Ws + (kb + kk) * 128 + c0);
            const float4 w1 = *(const float4*)(Ws + (kb + kk) * 128 + c0 + 4);
            const float wv[8] = {w0.x, w0.y, w0.z, w0.w, w1.x, w1.y, w1.z, w1.w};
#pragma unroll
            for (int i = 0; i < 4; i++) {
                const float f = fk[i][kk];
#pragma unroll
                for (int j = 0; j < 8; j++) acc[i][j] = fmaf(f, wv[j], acc[i][j]);
            }
        }
    }

    // c0 < 64 -> mu half (cols c0..c0+7 of Wmu); else logvar half
    const size_t lvoff = (size_t)nrows * 64;
    const float* bb = (c0 < 64) ? (bmu + c0) : (blv + (c0 - 64));
    float* obase    = (c0 < 64) ? out : (out + lvoff);
    const int oc    = (c0 < 64) ? c0 : (c0 - 64);
    const float4 b0 = *(const float4*)bb;
    const float4 b1v = *(const float4*)(bb + 4);
#pragma unroll
    for (int i = 0; i < 4; i++) {
        int r = r0 + i;
        if (r >= nrows) continue;
        float4 o0 = make_float4(acc[i][0] + b0.x, acc[i][1] + b0.y,
                                acc[i][2] + b0.z, acc[i][3] + b0.w);
        float4 o1 = make_float4(acc[i][4] + b1v.x, acc[i][5] + b1v.y,
                                acc[i][6] + b1v.z, acc[i][7] + b1v.w);
        *(float4*)(obase + (size_t)r * 64 + oc) = o0;
        *(float4*)(obase + (size_t)r * 64 + oc + 4) = o1;
    }
}

// -------------------- launcher --------------------
extern "C" void kernel_launch(void* const* d_in, const int* in_sizes, int n_in,
                              void* d_out, int out_size, void* d_ws, size_t ws_size,
                              hipStream_t stream) {
    const float* x   = (const float*)d_in[0];
    const int*   ei  = (const int*)d_in[1];
    const float* W1  = (const float*)d_in[2];
    const float* b1  = (const float*)d_in[3];
    const float* Wmu = (const float*)d_in[4];
    const float* bmu = (const float*)d_in[5];
    const float* Wlv = (const float*)d_in[6];
    const float* blv = (const float*)d_in[7];
    float* out = (float*)d_out;

    const int N = in_sizes[0] / 128;
    const int E = in_sizes[1] / 2;
    const int* src = ei;
    const int* dst = ei + E;

    char* ws = (char*)d_ws;
    float* dinv = (float*)ws;
    size_t off = ws_align((size_t)N * sizeof(float));
    float* F = (float*)(ws + off);                       // [N,128] agg1 -> h
    float* G = (float*)(ws + off + (size_t)N * 512);     // [N,128] agg2

    const int b = 256;
    k_deg_init<<<(N + b - 1) / b, b, 0, stream>>>(dinv, N);
    k_deg_acc<<<(E + b - 1) / b, b, 0, stream>>>(dst, dinv, E);
    k_rsqrt<<<(N + b - 1) / b, b, 0, stream>>>(dinv, N);

    const int n32 = N * 32;
    // layer 1 aggregation: F = D^-1/2 (A+I) D^-1/2 x
    k_self_init<<<(n32 + b - 1) / b, b, 0, stream>>>(x, dinv, F, n32);
    k_scatter<<<(E + 3) / 4, 256, 0, stream>>>(x, F, src, dst, dinv, E);
    // h = relu(F @ W1 + b1), in place
    k_gemm_relu_inplace<<<(N + 63) / 64, 256, 0, stream>>>(F, W1, b1, N);
    // layer 2 aggregation: G = D^-1/2 (A+I) D^-1/2 h
    k_self_init<<<(n32 + b - 1) / b, b, 0, stream>>>(F, dinv, G, n32);
    k_scatter<<<(E + 3) / 4, 256, 0, stream>>>(F, G, src, dst, dinv, E);
    // mu | logvar = G @ [Wmu|Wlv] + bias, written straight into d_out's split layout
    k_gemm_out<<<(N + 63) / 64, 256, 0, stream>>>(G, Wmu, Wlv, bmu, blv, out, N);
}

// Round 2
// 625.510 us; speedup vs baseline: 4.6990x; 4.6990x over previous
//
#include <hip/hip_runtime.h>
#include <hip/hip_bf16.h>

static inline size_t ws_align(size_t x) { return (x + 255) & ~(size_t)255; }

// -------------------- degree histogram (int) --------------------
__global__ void k_hist(const int* __restrict__ dst, int* __restrict__ cnt, int E) {
    int e = blockIdx.x * blockDim.x + threadIdx.x;
    if (e < E) atomicAdd(&cnt[dst[e]], 1);
}

// dinv[i] = rsqrt(cnt[i] + 1)   (self-loop adds 1)
__global__ void k_dinv(const int* __restrict__ cnt, float* __restrict__ dinv, int N) {
    int i = blockIdx.x * blockDim.x + threadIdx.x;
    if (i < N) dinv[i] = rsqrtf((float)(cnt[i] + 1));
}

// -------------------- exclusive scan (3 kernels, 1024 elems/block) --------------------
__global__ __launch_bounds__(256) void k_scan1(const int* __restrict__ cnt, int* __restrict__ rp,
                                               int* __restrict__ bsum, int N) {
    __shared__ int sh[256];
    int t = threadIdx.x;
    int base = blockIdx.x * 1024 + t * 4;
    int v[4];
#pragma unroll
    for (int i = 0; i < 4; i++) v[i] = (base + i < N) ? cnt[base + i] : 0;
    int s = v[0] + v[1] + v[2] + v[3];
    sh[t] = s;
    __syncthreads();
    for (int off = 1; off < 256; off <<= 1) {
        int x = (t >= off) ? sh[t - off] : 0;
        __syncthreads();
        sh[t] += x;
        __syncthreads();
    }
    int excl = sh[t] - s;
    if (t == 255) bsum[blockIdx.x] = sh[255];
    int run = excl;
#pragma unroll
    for (int i = 0; i < 4; i++) {
        if (base + i < N) rp[base + i] = run;
        run += v[i];
    }
}

__global__ __launch_bounds__(256) void k_scan2(int* __restrict__ bsum, int nb) {
    __shared__ int sh[256];
    int t = threadIdx.x;
    int v = (t < nb) ? bsum[t] : 0;
    sh[t] = v;
    __syncthreads();
    for (int off = 1; off < 256; off <<= 1) {
        int x = (t >= off) ? sh[t - off] : 0;
        __syncthreads();
        sh[t] += x;
        __syncthreads();
    }
    if (t < nb) bsum[t] = sh[t] - v;  // exclusive
}

__global__ void k_scan3(int* __restrict__ rp, const int* __restrict__ bsum, int N, int E) {
    int i = blockIdx.x * blockDim.x + threadIdx.x;
    if (i < N) rp[i] += bsum[i >> 10];
    if (i == N) rp[N] = E;
}

// -------------------- CSR fill: place each edge in its dst bucket --------------------
__global__ void k_fill(const int* __restrict__ src, const int* __restrict__ dst,
                       const float* __restrict__ dinv, const int* __restrict__ rp,
                       int* __restrict__ fill, int* __restrict__ csrc,
                       float* __restrict__ cw, int E) {
    int e = blockIdx.x * blockDim.x + threadIdx.x;
    if (e >= E) return;
    int s = src[e], d = dst[e];
    int pos = rp[d] + atomicAdd(&fill[d], 1);
    csrc[pos] = s;
    cw[pos] = dinv[s] * dinv[d];
}

// -------------------- aggregation: one wave per dst node, gather + single write --------------------
// out[d][:] = dinv[d]^2 * feat[d][:] + sum_e cw[e] * feat[csrc[e]][:]
__global__ __launch_bounds__(256) void k_agg(const float* __restrict__ feat, float* __restrict__ out,
                                             const int* __restrict__ rp, const int* __restrict__ csrc,
                                             const float* __restrict__ cw,
                                             const float* __restrict__ dinv, int N) {
    int node = blockIdx.x * 4 + (threadIdx.x >> 6);
    if (node >= N) return;
    int lane = threadIdx.x & 63;
    const size_t fo = (size_t)lane * 2;
    int beg = rp[node], end = rp[node + 1];
    float di = dinv[node];
    float w0 = di * di;
    float2 v0 = *(const float2*)(feat + (size_t)node * 128 + fo);
    float ax = v0.x * w0, ay = v0.y * w0;
    int e = beg;
    for (; e + 1 < end; e += 2) {
        int s0 = csrc[e], s1 = csrc[e + 1];
        float wa = cw[e], wb = cw[e + 1];
        float2 a = *(const float2*)(feat + (size_t)s0 * 128 + fo);
        float2 b = *(const float2*)(feat + (size_t)s1 * 128 + fo);
        ax = fmaf(a.x, wa, ax);
        ay = fmaf(a.y, wa, ay);
        ax = fmaf(b.x, wb, ax);
        ay = fmaf(b.y, wb, ay);
    }
    if (e < end) {
        int s0 = csrc[e];
        float wa = cw[e];
        float2 a = *(const float2*)(feat + (size_t)s0 * 128 + fo);
        ax = fmaf(a.x, wa, ax);
        ay = fmaf(a.y, wa, ay);
    }
    *(float2*)(out + (size_t)node * 128 + fo) = make_float2(ax, ay);
}

// -------------------- GEMM1: F = relu(F @ W + b), in-place, W is 128x128 --------------------
__global__ __launch_bounds__(256) void k_gemm_relu_inplace(
        float* __restrict__ F, const float* __restrict__ W,
        const float* __restrict__ b, int nrows) {
    __shared__ float Ws[128 * 128];
    for (int t = threadIdx.x; t < 128 * 128 / 4; t += 256)
        ((float4*)Ws)[t] = ((const float4*)W)[t];
    __syncthreads();

    const int ty = threadIdx.x >> 4, tx = threadIdx.x & 15;
    const int r0 = blockIdx.x * 64 + ty * 4;
    const int c0 = tx * 8;

    float acc[4][8];
#pragma unroll
    for (int i = 0; i < 4; i++)
#pragma unroll
        for (int j = 0; j < 8; j++) acc[i][j] = 0.0f;

    for (int kb = 0; kb < 128; kb += 4) {
        float fk[4][4];
#pragma unroll
        for (int i = 0; i < 4; i++) {
            int r = r0 + i;
            float4 a = (r < nrows) ? *(const float4*)(F + (size_t)r * 128 + kb)
                                   : make_float4(0.f, 0.f, 0.f, 0.f);
            fk[i][0] = a.x; fk[i][1] = a.y; fk[i][2] = a.z; fk[i][3] = a.w;
        }
#pragma unroll
        for (int kk = 0; kk < 4; kk++) {
            const float4 w0 = *(const float4*)(Ws + (kb + kk) * 128 + c0);
            const float4 w1 = *(const float4*)(Ws + (kb + kk) * 128 + c0 + 4);
            const float wv[8] = {w0.x, w0.y, w0.z, w0.w, w1.x, w1.y, w1.z, w1.w};
#pragma unroll
            for (int i = 0; i < 4; i++) {
                const float f = fk[i][kk];
#pragma unroll
                for (int j = 0; j < 8; j++) acc[i][j] = fmaf(f, wv[j], acc[i][j]);
            }
        }
    }

    const float4 b0 = *(const float4*)(b + c0);
    const float4 b1v = *(const float4*)(b + c0 + 4);
#pragma unroll
    for (int i = 0; i < 4; i++) {
        int r = r0 + i;
        if (r >= nrows) continue;
        float4 o0 = make_float4(fmaxf(acc[i][0] + b0.x, 0.f), fmaxf(acc[i][1] + b0.y, 0.f),
                                fmaxf(acc[i][2] + b0.z, 0.f), fmaxf(acc[i][3] + b0.w, 0.f));
        float4 o1 = make_float4(fmaxf(acc[i][4] + b1v.x, 0.f), fmaxf(acc[i][5] + b1v.y, 0.f),
                                fmaxf(acc[i][6] + b1v.z, 0.f), fmaxf(acc[i][7] + b1v.w, 0.f));
        *(float4*)(F + (size_t)r * 128 + c0) = o0;
        *(float4*)(F + (size_t)r * 128 + c0 + 4) = o1;
    }
}

// -------------------- GEMM2: out = G @ [Wmu | Wlv] + [bmu | blv], split-write --------------------
__global__ __launch_bounds__(256) void k_gemm_out(
        const float* __restrict__ G,
        const float* __restrict__ Wmu, const float* __restrict__ Wlv,
        const float* __restrict__ bmu, const float* __restrict__ blv,
        float* __restrict__ out, int nrows) {
    __shared__ float Ws[128 * 128];
    for (int t = threadIdx.x; t < 128 * 16; t += 256) {
        int k = t >> 4, jq = t & 15;
        ((float4*)(Ws + k * 128))[jq]      = ((const float4*)(Wmu + k * 64))[jq];
        ((float4*)(Ws + k * 128 + 64))[jq] = ((const float4*)(Wlv + k * 64))[jq];
    }
    __syncthreads();

    const int ty = threadIdx.x >> 4, tx = threadIdx.x & 15;
    const int r0 = blockIdx.x * 64 + ty * 4;
    const int c0 = tx * 8;

    float acc[4][8];
#pragma unroll
    for (int i = 0; i < 4; i++)
#pragma unroll
        for (int j = 0; j < 8; j++) acc[i][j] = 0.0f;

    for (int kb = 0; kb < 128; kb += 4) {
        float fk[4][4];
#pragma unroll
        for (int i = 0; i < 4; i++) {
            int r = r0 + i;
            float4 a = (r < nrows) ? *(const float4*)(G + (size_t)r * 128 + kb)
                                   : make_float4(0.f, 0.f, 0.f, 0.f);
            fk[i][0] = a.x; fk[i][1] = a.y; fk[i][2] = a.z; fk[i][3] = a.w;
        }
#pragma unroll
        for (int kk = 0; kk < 4; kk++) {
            const float4 w0 = *(const float4*)(Ws + (kb + kk) * 128 + c0);
            const float4 w1 = *(const float4*)(Ws + (kb + kk) * 128 + c0 + 4);
            const float wv[8] = {w0.x, w0.y, w0.z, w0.w, w1.x, w1.y, w1.z, w1.w};
#pragma unroll
            for (int i = 0; i < 4; i++) {
                const float f = fk[i][kk];
#pragma unroll
                for (int j = 0; j < 8; j++) acc[i][j] = fmaf(f, wv[j], acc[i][j]);
            }
        }
    }

    const size_t lvoff = (size_t)nrows * 64;
    const float* bb = (c0 < 64) ? (bmu + c0) : (blv + (c0 - 64));
    float* obase    = (c0 < 64) ? out : (out + lvoff);
    const int oc    = (c0 < 64) ? c0 : (c0 - 64);
    const float4 b0 = *(const float4*)bb;
    const float4 b1v = *(const float4*)(bb + 4);
#pragma unroll
    for (int i = 0; i < 4; i++) {
        int r = r0 + i;
        if (r >= nrows) continue;
        float4 o0 = make_float4(acc[i][0] + b0.x, acc[i][1] + b0.y,
                                acc[i][2] + b0.z, acc[i][3] + b0.w);
        float4 o1 = make_float4(acc[i][4] + b1v.x, acc[i][5] + b1v.y,
                                acc[i][6] + b1v.z, acc[i][7] + b1v.w);
        *(float4*)(obase + (size_t)r * 64 + oc) = o0;
        *(float4*)(obase + (size_t)r * 64 + oc + 4) = o1;
    }
}

// -------------------- launcher --------------------
extern "C" void kernel_launch(void* const* d_in, const int* in_sizes, int n_in,
                              void* d_out, int out_size, void* d_ws, size_t ws_size,
                              hipStream_t stream) {
    const float* x   = (const float*)d_in[0];
    const int*   ei  = (const int*)d_in[1];
    const float* W1  = (const float*)d_in[2];
    const float* b1  = (const float*)d_in[3];
    const float* Wmu = (const float*)d_in[4];
    const float* bmu = (const float*)d_in[5];
    const float* Wlv = (const float*)d_in[6];
    const float* blv = (const float*)d_in[7];
    float* out = (float*)d_out;

    const int N = in_sizes[0] / 128;
    const int E = in_sizes[1] / 2;
    const int* src = ei;
    const int* dst = ei + E;

    // workspace layout (~66 MB)
    char* ws = (char*)d_ws;
    size_t off = 0;
    float* dinv = (float*)(ws + off); off = ws_align(off + (size_t)N * 4);
    int* cnt    = (int*)(ws + off);   off = ws_align(off + (size_t)N * 4);
    int* rp     = (int*)(ws + off);   off = ws_align(off + (size_t)(N + 1) * 4);
    int* fill   = (int*)(ws + off);   off = ws_align(off + (size_t)N * 4);
    int* csrc   = (int*)(ws + off);   off = ws_align(off + (size_t)E * 4);
    float* cw   = (float*)(ws + off); off = ws_align(off + (size_t)E * 4);
    float* G    = (float*)(ws + off); off = ws_align(off + (size_t)N * 512);
    float* F    = out;  // N*128 == out_size; dead before k_gemm_out writes out

    const int b = 256;
    const int nbN = (N + b - 1) / b;
    const int nbE = (E + b - 1) / b;
    const int nscan = (N + 1023) / 1024;

    // ---- build CSR (by dst) + dinv ----
    hipMemsetAsync(cnt, 0, (size_t)N * 4, stream);
    hipMemsetAsync(fill, 0, (size_t)N * 4, stream);
    k_hist<<<nbE, b, 0, stream>>>(dst, cnt, E);
    k_dinv<<<nbN, b, 0, stream>>>(cnt, dinv, N);
    k_scan1<<<nscan, 256, 0, stream>>>(cnt, rp, fill + 0, N);  // reuse? no: need fill zeroed later
    // NOTE: use cnt as block-sum scratch is unsafe (cnt still needed? no, dinv done) — but keep
    // a dedicated small region: reuse tail of G (not yet written) for block sums.
    // Simpler: bsum lives in G's first nscan ints (G written later).
    // Redo scan properly below with bsum = (int*)G.
    // (the k_scan1 call above already wrote rp and bsum into fill -- fix: re-run with proper bsum)
    k_scan1<<<nscan, 256, 0, stream>>>(cnt, rp, (int*)G, N);
    k_scan2<<<1, 256, 0, stream>>>((int*)G, nscan);
    k_scan3<<<(N + 1 + b - 1) / b, b, 0, stream>>>(rp, (const int*)G, N, E);
    hipMemsetAsync(fill, 0, (size_t)N * 4, stream);  // re-zero (first scan1 clobbered it)
    k_fill<<<nbE, b, 0, stream>>>(src, dst, dinv, rp, fill, csrc, cw, E);

    // ---- layer 1: F = Â x ; F = relu(F @ W1 + b1) ----
    const int aggBlocks = (N + 3) / 4;
    k_agg<<<aggBlocks, 256, 0, stream>>>(x, F, rp, csrc, cw, dinv, N);
    k_gemm_relu_inplace<<<(N + 63) / 64, 256, 0, stream>>>(F, W1, b1, N);

    // ---- layer 2: G = Â h ; out = G @ [Wmu|Wlv] + bias ----
    k_agg<<<aggBlocks, 256, 0, stream>>>(F, G, rp, csrc, cw, dinv, N);
    k_gemm_out<<<(N + 63) / 64, 256, 0, stream>>>(G, Wmu, Wlv, bmu, blv, out, N);
}

// Round 3
// 527.808 us; speedup vs baseline: 5.5689x; 1.1851x over previous
//
#include <hip/hip_runtime.h>
#include <hip/hip_bf16.h>
#include <stdint.h>

static inline size_t ws_align(size_t x) { return (x + 255) & ~(size_t)255; }

// RTNE f32 -> bf16 pair packed into uint32 (elem0 in low 16)
__device__ __forceinline__ uint32_t pack_bf16(float a, float b) {
    uint32_t ua = __float_as_uint(a), ub = __float_as_uint(b);
    ua = (ua + 0x7fffu + ((ua >> 16) & 1u)) >> 16;
    ub = (ub + 0x7fffu + ((ub >> 16) & 1u)) >> 16;
    return ua | (ub << 16);
}
__device__ __forceinline__ float bf_lo(uint32_t v) { return __uint_as_float(v << 16); }
__device__ __forceinline__ float bf_hi(uint32_t v) { return __uint_as_float(v & 0xffff0000u); }

// -------------------- degree histogram --------------------
__global__ void k_hist(const int* __restrict__ dst, int* __restrict__ cnt, int E) {
    int e = blockIdx.x * blockDim.x + threadIdx.x;
    if (e < E) atomicAdd(&cnt[dst[e]], 1);
}

__global__ void k_dinv(const int* __restrict__ cnt, float* __restrict__ dinv, int N) {
    int i = blockIdx.x * blockDim.x + threadIdx.x;
    if (i < N) dinv[i] = rsqrtf((float)(cnt[i] + 1));
}

// -------------------- exclusive scan --------------------
__global__ __launch_bounds__(256) void k_scan1(const int* __restrict__ cnt, int* __restrict__ rp,
                                               int* __restrict__ bsum, int N) {
    __shared__ int sh[256];
    int t = threadIdx.x;
    int base = blockIdx.x * 1024 + t * 4;
    int v[4];
#pragma unroll
    for (int i = 0; i < 4; i++) v[i] = (base + i < N) ? cnt[base + i] : 0;
    int s = v[0] + v[1] + v[2] + v[3];
    sh[t] = s;
    __syncthreads();
    for (int off = 1; off < 256; off <<= 1) {
        int x = (t >= off) ? sh[t - off] : 0;
        __syncthreads();
        sh[t] += x;
        __syncthreads();
    }
    int excl = sh[t] - s;
    if (t == 255) bsum[blockIdx.x] = sh[255];
    int run = excl;
#pragma unroll
    for (int i = 0; i < 4; i++) {
        if (base + i < N) rp[base + i] = run;
        run += v[i];
    }
}

__global__ __launch_bounds__(256) void k_scan2(int* __restrict__ bsum, int nb) {
    __shared__ int sh[256];
    int t = threadIdx.x;
    int v = (t < nb) ? bsum[t] : 0;
    sh[t] = v;
    __syncthreads();
    for (int off = 1; off < 256; off <<= 1) {
        int x = (t >= off) ? sh[t - off] : 0;
        __syncthreads();
        sh[t] += x;
        __syncthreads();
    }
    if (t < nb) bsum[t] = sh[t] - v;
}

__global__ void k_scan3(int* __restrict__ rp, const int* __restrict__ bsum, int N, int E) {
    int i = blockIdx.x * blockDim.x + threadIdx.x;
    if (i < N) rp[i] += bsum[i >> 10];
    if (i == N) rp[N] = E;
}

// -------------------- CSR fill --------------------
__global__ void k_fill(const int* __restrict__ src, const int* __restrict__ dst,
                       const float* __restrict__ dinv, const int* __restrict__ rp,
                       int* __restrict__ fill, int* __restrict__ csrc,
                       float* __restrict__ cw, int E) {
    int e = blockIdx.x * blockDim.x + threadIdx.x;
    if (e >= E) return;
    int s = src[e], d = dst[e];
    int pos = rp[d] + atomicAdd(&fill[d], 1);
    csrc[pos] = s;
    cw[pos] = dinv[s] * dinv[d];
}

// -------------------- f32 -> packed bf16 convert (n4 = N*32 float4's) --------------------
__global__ void k_cvt(const float* __restrict__ in, uint32_t* __restrict__ outp, int n4) {
    int idx = blockIdx.x * blockDim.x + threadIdx.x;
    if (idx >= n4) return;
    float4 v = ((const float4*)in)[idx];
    ((uint2*)outp)[idx] = make_uint2(pack_bf16(v.x, v.y), pack_bf16(v.z, v.w));
}

// -------------------- aggregation over bf16 features --------------------
// featB: packed bf16 rows (128 bf16 = 256B payload) at row stride `strideB` bytes.
// outF[d][:] = dinv[d]^2 * feat[d][:] + sum_e cw[e] * feat[csrc[e]][:]   (f32 accumulate)
__global__ __launch_bounds__(256) void k_agg(const uint8_t* __restrict__ featB, size_t strideB,
                                             float* __restrict__ outF,
                                             const int* __restrict__ rp, const int* __restrict__ csrc,
                                             const float* __restrict__ cw,
                                             const float* __restrict__ dinv, int N) {
    int node = blockIdx.x * 4 + (threadIdx.x >> 6);
    if (node >= N) return;
    int lane = threadIdx.x & 63;
    const uint32_t off = lane * 4;   // dword per lane: bf16 cols {2*lane, 2*lane+1}
    int beg = rp[node], end = rp[node + 1];
    float di = dinv[node];
    float w0 = di * di;
    uint32_t v0 = *(const uint32_t*)(featB + (size_t)node * strideB + off);
    float ax = bf_lo(v0) * w0, ay = bf_hi(v0) * w0;
    int e = beg;
    for (; e + 4 <= end; e += 4) {
        int s0 = csrc[e], s1 = csrc[e + 1], s2 = csrc[e + 2], s3 = csrc[e + 3];
        float wa = cw[e], wb = cw[e + 1], wc = cw[e + 2], wd = cw[e + 3];
        uint32_t g0 = *(const uint32_t*)(featB + (size_t)s0 * strideB + off);
        uint32_t g1 = *(const uint32_t*)(featB + (size_t)s1 * strideB + off);
        uint32_t g2 = *(const uint32_t*)(featB + (size_t)s2 * strideB + off);
        uint32_t g3 = *(const uint32_t*)(featB + (size_t)s3 * strideB + off);
        ax = fmaf(bf_lo(g0), wa, ax); ay = fmaf(bf_hi(g0), wa, ay);
        ax = fmaf(bf_lo(g1), wb, ax); ay = fmaf(bf_hi(g1), wb, ay);
        ax = fmaf(bf_lo(g2), wc, ax); ay = fmaf(bf_hi(g2), wc, ay);
        ax = fmaf(bf_lo(g3), wd, ax); ay = fmaf(bf_hi(g3), wd, ay);
    }
    for (; e < end; ++e) {
        int s0 = csrc[e];
        float wa = cw[e];
        uint32_t g0 = *(const uint32_t*)(featB + (size_t)s0 * strideB + off);
        ax = fmaf(bf_lo(g0), wa, ax); ay = fmaf(bf_hi(g0), wa, ay);
    }
    *(float2*)(outF + (size_t)node * 128 + lane * 2) = make_float2(ax, ay);
}

// -------------------- GEMM1: h = relu(F @ W + b); writes h as packed bf16 in-row --------------------
// Reads f32 rows of F; epilogue writes 128 bf16 (256B) at each row's base (byte r*512).
// Safe in-place: a row's 128 cols are read only by threads of ONE wave, and all k-loop
// reads complete (lockstep) before any epilogue write of that wave.
__global__ __launch_bounds__(256) void k_gemm_relu_bf16(
        const float* __restrict__ F, uint8_t* __restrict__ HB,
        const float* __restrict__ W, const float* __restrict__ b, int nrows) {
    __shared__ float Ws[128 * 128];
    for (int t = threadIdx.x; t < 128 * 128 / 4; t += 256)
        ((float4*)Ws)[t] = ((const float4*)W)[t];
    __syncthreads();

    const int ty = threadIdx.x >> 4, tx = threadIdx.x & 15;
    const int r0 = blockIdx.x * 64 + ty * 4;
    const int c0 = tx * 8;

    float acc[4][8];
#pragma unroll
    for (int i = 0; i < 4; i++)
#pragma unroll
        for (int j = 0; j < 8; j++) acc[i][j] = 0.0f;

    for (int kb = 0; kb < 128; kb += 4) {
        float fk[4][4];
#pragma unroll
        for (int i = 0; i < 4; i++) {
            int r = r0 + i;
            float4 a = (r < nrows) ? *(const float4*)(F + (size_t)r * 128 + kb)
                                   : make_float4(0.f, 0.f, 0.f, 0.f);
            fk[i][0] = a.x; fk[i][1] = a.y; fk[i][2] = a.z; fk[i][3] = a.w;
        }
#pragma unroll
        for (int kk = 0; kk < 4; kk++) {
            const float4 w0 = *(const float4*)(Ws + (kb + kk) * 128 + c0);
            const float4 w1 = *(const float4*)(Ws + (kb + kk) * 128 + c0 + 4);
            const float wv[8] = {w0.x, w0.y, w0.z, w0.w, w1.x, w1.y, w1.z, w1.w};
#pragma unroll
            for (int i = 0; i < 4; i++) {
                const float f = fk[i][kk];
#pragma unroll
                for (int j = 0; j < 8; j++) acc[i][j] = fmaf(f, wv[j], acc[i][j]);
            }
        }
    }

    const float4 b0 = *(const float4*)(b + c0);
    const float4 b1v = *(const float4*)(b + c0 + 4);
    const float bb[8] = {b0.x, b0.y, b0.z, b0.w, b1v.x, b1v.y, b1v.z, b1v.w};
#pragma unroll
    for (int i = 0; i < 4; i++) {
        int r = r0 + i;
        if (r >= nrows) continue;
        float h[8];
#pragma unroll
        for (int j = 0; j < 8; j++) h[j] = fmaxf(acc[i][j] + bb[j], 0.f);
        uint4 p = make_uint4(pack_bf16(h[0], h[1]), pack_bf16(h[2], h[3]),
                             pack_bf16(h[4], h[5]), pack_bf16(h[6], h[7]));
        *(uint4*)(HB + (size_t)r * 512 + (size_t)c0 * 2) = p;
    }
}

// -------------------- GEMM2: out = G @ [Wmu | Wlv] + [bmu | blv] --------------------
__global__ __launch_bounds__(256) void k_gemm_out(
        const float* __restrict__ G,
        const float* __restrict__ Wmu, const float* __restrict__ Wlv,
        const float* __restrict__ bmu, const float* __restrict__ blv,
        float* __restrict__ out, int nrows) {
    __shared__ float Ws[128 * 128];
    for (int t = threadIdx.x; t < 128 * 16; t += 256) {
        int k = t >> 4, jq = t & 15;
        ((float4*)(Ws + k * 128))[jq]      = ((const float4*)(Wmu + k * 64))[jq];
        ((float4*)(Ws + k * 128 + 64))[jq] = ((const float4*)(Wlv + k * 64))[jq];
    }
    __syncthreads();

    const int ty = threadIdx.x >> 4, tx = threadIdx.x & 15;
    const int r0 = blockIdx.x * 64 + ty * 4;
    const int c0 = tx * 8;

    float acc[4][8];
#pragma unroll
    for (int i = 0; i < 4; i++)
#pragma unroll
        for (int j = 0; j < 8; j++) acc[i][j] = 0.0f;

    for (int kb = 0; kb < 128; kb += 4) {
        float fk[4][4];
#pragma unroll
        for (int i = 0; i < 4; i++) {
            int r = r0 + i;
            float4 a = (r < nrows) ? *(const float4*)(G + (size_t)r * 128 + kb)
                                   : make_float4(0.f, 0.f, 0.f, 0.f);
            fk[i][0] = a.x; fk[i][1] = a.y; fk[i][2] = a.z; fk[i][3] = a.w;
        }
#pragma unroll
        for (int kk = 0; kk < 4; kk++) {
            const float4 w0 = *(const float4*)(Ws + (kb + kk) * 128 + c0);
            const float4 w1 = *(const float4*)(Ws + (kb + kk) * 128 + c0 + 4);
            const float wv[8] = {w0.x, w0.y, w0.z, w0.w, w1.x, w1.y, w1.z, w1.w};
#pragma unroll
            for (int i = 0; i < 4; i++) {
                const float f = fk[i][kk];
#pragma unroll
                for (int j = 0; j < 8; j++) acc[i][j] = fmaf(f, wv[j], acc[i][j]);
            }
        }
    }

    const size_t lvoff = (size_t)nrows * 64;
    const float* bb = (c0 < 64) ? (bmu + c0) : (blv + (c0 - 64));
    float* obase    = (c0 < 64) ? out : (out + lvoff);
    const int oc    = (c0 < 64) ? c0 : (c0 - 64);
    const float4 b0 = *(const float4*)bb;
    const float4 b1v = *(const float4*)(bb + 4);
#pragma unroll
    for (int i = 0; i < 4; i++) {
        int r = r0 + i;
        if (r >= nrows) continue;
        float4 o0 = make_float4(acc[i][0] + b0.x, acc[i][1] + b0.y,
                                acc[i][2] + b0.z, acc[i][3] + b0.w);
        float4 o1 = make_float4(acc[i][4] + b1v.x, acc[i][5] + b1v.y,
                                acc[i][6] + b1v.z, acc[i][7] + b1v.w);
        *(float4*)(obase + (size_t)r * 64 + oc) = o0;
        *(float4*)(obase + (size_t)r * 64 + oc + 4) = o1;
    }
}

// -------------------- launcher --------------------
extern "C" void kernel_launch(void* const* d_in, const int* in_sizes, int n_in,
                              void* d_out, int out_size, void* d_ws, size_t ws_size,
                              hipStream_t stream) {
    const float* x   = (const float*)d_in[0];
    const int*   ei  = (const int*)d_in[1];
    const float* W1  = (const float*)d_in[2];
    const float* b1  = (const float*)d_in[3];
    const float* Wmu = (const float*)d_in[4];
    const float* bmu = (const float*)d_in[5];
    const float* Wlv = (const float*)d_in[6];
    const float* blv = (const float*)d_in[7];
    float* out = (float*)d_out;

    const int N = in_sizes[0] / 128;
    const int E = in_sizes[1] / 2;
    const int* src = ei;
    const int* dst = ei + E;

    // workspace (~66 MB, same footprint as the proven round-2 layout)
    char* ws = (char*)d_ws;
    size_t off = 0;
    float* dinv = (float*)(ws + off); off = ws_align(off + (size_t)N * 4);
    int* cnt    = (int*)(ws + off);   off = ws_align(off + (size_t)N * 4);
    int* rp     = (int*)(ws + off);   off = ws_align(off + (size_t)(N + 1) * 4);
    int* fill   = (int*)(ws + off);   off = ws_align(off + (size_t)N * 4);
    int* csrc   = (int*)(ws + off);   off = ws_align(off + (size_t)E * 4);
    float* cw   = (float*)(ws + off); off = ws_align(off + (size_t)E * 4);
    float* G    = (float*)(ws + off); off = ws_align(off + (size_t)N * 512);
    // x-as-bf16 lives in G's buffer (dead until agg2 writes G)
    uint32_t* xb = (uint32_t*)G;            // N*128 bf16 = 25.6 MB, stride 256 B
    float* F = out;                          // agg1 output f32 (N*128 == out_size)
    uint8_t* HB = (uint8_t*)out;             // h as packed bf16, row stride 512 B

    const int b = 256;
    const int nbN = (N + b - 1) / b;
    const int nbE = (E + b - 1) / b;
    const int nscan = (N + 1023) / 1024;

    // ---- CSR build (bsum scratch = cw, overwritten later by k_fill) ----
    hipMemsetAsync(cnt, 0, (size_t)N * 4, stream);
    hipMemsetAsync(fill, 0, (size_t)N * 4, stream);
    k_hist<<<nbE, b, 0, stream>>>(dst, cnt, E);
    k_dinv<<<nbN, b, 0, stream>>>(cnt, dinv, N);
    k_scan1<<<nscan, 256, 0, stream>>>(cnt, rp, (int*)cw, N);
    k_scan2<<<1, 256, 0, stream>>>((int*)cw, nscan);
    k_scan3<<<(N + 1 + b - 1) / b, b, 0, stream>>>(rp, (const int*)cw, N, E);
    k_fill<<<nbE, b, 0, stream>>>(src, dst, dinv, rp, fill, csrc, cw, E);

    // ---- layer 1 ----
    k_cvt<<<(N * 32 + b - 1) / b, b, 0, stream>>>(x, xb, N * 32);
    const int aggBlocks = (N + 3) / 4;
    k_agg<<<aggBlocks, 256, 0, stream>>>((const uint8_t*)xb, 256, F, rp, csrc, cw, dinv, N);
    k_gemm_relu_bf16<<<(N + 63) / 64, 256, 0, stream>>>(F, HB, W1, b1, N);

    // ---- layer 2 ----
    k_agg<<<aggBlocks, 256, 0, stream>>>(HB, 512, G, rp, csrc, cw, dinv, N);
    k_gemm_out<<<(N + 63) / 64, 256, 0, stream>>>(G, Wmu, Wlv, bmu, blv, out, N);
}

// Round 4
// 489.511 us; speedup vs baseline: 6.0045x; 1.0782x over previous
//
#include <hip/hip_runtime.h>
#include <hip/hip_bf16.h>
#include <stdint.h>

static inline size_t ws_align(size_t x) { return (x + 255) & ~(size_t)255; }

// RTNE f32 -> bf16 pair packed into uint32 (elem0 in low 16)
__device__ __forceinline__ uint32_t pack_bf16(float a, float b) {
    uint32_t ua = __float_as_uint(a), ub = __float_as_uint(b);
    ua = (ua + 0x7fffu + ((ua >> 16) & 1u)) >> 16;
    ub = (ub + 0x7fffu + ((ub >> 16) & 1u)) >> 16;
    return ua | (ub << 16);
}
__device__ __forceinline__ float bf_lo(uint32_t v) { return __uint_as_float(v << 16); }
__device__ __forceinline__ float bf_hi(uint32_t v) { return __uint_as_float(v & 0xffff0000u); }

// -------------------- degree histogram --------------------
__global__ void k_hist(const int* __restrict__ dst, int* __restrict__ cnt, int E) {
    int e = blockIdx.x * blockDim.x + threadIdx.x;
    if (e < E) atomicAdd(&cnt[dst[e]], 1);
}

__global__ void k_dinv(const int* __restrict__ cnt, float* __restrict__ dinv, int N) {
    int i = blockIdx.x * blockDim.x + threadIdx.x;
    if (i < N) dinv[i] = rsqrtf((float)(cnt[i] + 1));
}

// -------------------- exclusive scan --------------------
__global__ __launch_bounds__(256) void k_scan1(const int* __restrict__ cnt, int* __restrict__ rp,
                                               int* __restrict__ bsum, int N) {
    __shared__ int sh[256];
    int t = threadIdx.x;
    int base = blockIdx.x * 1024 + t * 4;
    int v[4];
#pragma unroll
    for (int i = 0; i < 4; i++) v[i] = (base + i < N) ? cnt[base + i] : 0;
    int s = v[0] + v[1] + v[2] + v[3];
    sh[t] = s;
    __syncthreads();
    for (int off = 1; off < 256; off <<= 1) {
        int x = (t >= off) ? sh[t - off] : 0;
        __syncthreads();
        sh[t] += x;
        __syncthreads();
    }
    int excl = sh[t] - s;
    if (t == 255) bsum[blockIdx.x] = sh[255];
    int run = excl;
#pragma unroll
    for (int i = 0; i < 4; i++) {
        if (base + i < N) rp[base + i] = run;
        run += v[i];
    }
}

__global__ __launch_bounds__(256) void k_scan2(int* __restrict__ bsum, int nb) {
    __shared__ int sh[256];
    int t = threadIdx.x;
    int v = (t < nb) ? bsum[t] : 0;
    sh[t] = v;
    __syncthreads();
    for (int off = 1; off < 256; off <<= 1) {
        int x = (t >= off) ? sh[t - off] : 0;
        __syncthreads();
        sh[t] += x;
        __syncthreads();
    }
    if (t < nb) bsum[t] = sh[t] - v;
}

__global__ void k_scan3(int* __restrict__ rp, const int* __restrict__ bsum, int N, int E) {
    int i = blockIdx.x * blockDim.x + threadIdx.x;
    if (i < N) rp[i] += bsum[i >> 10];
    if (i == N) rp[N] = E;
}

// -------------------- CSR fill: one 8-B write per edge (src, weight) --------------------
__global__ void k_fill(const int* __restrict__ src, const int* __restrict__ dst,
                       const float* __restrict__ dinv, const int* __restrict__ rp,
                       int* __restrict__ fill, uint2* __restrict__ cedge, int E) {
    int e = blockIdx.x * blockDim.x + threadIdx.x;
    if (e >= E) return;
    int s = src[e], d = dst[e];
    int pos = rp[d] + atomicAdd(&fill[d], 1);
    cedge[pos] = make_uint2((uint32_t)s, __float_as_uint(dinv[s] * dinv[d]));
}

// -------------------- f32 -> packed bf16 convert --------------------
__global__ void k_cvt(const float* __restrict__ in, uint32_t* __restrict__ outp, int n4) {
    int idx = blockIdx.x * blockDim.x + threadIdx.x;
    if (idx >= n4) return;
    float4 v = ((const float4*)in)[idx];
    ((uint2*)outp)[idx] = make_uint2(pack_bf16(v.x, v.y), pack_bf16(v.z, v.w));
}

// -------------------- aggregation over bf16 features --------------------
// outF[d][:] = dinv[d]^2 * feat[d][:] + sum_e w[e] * feat[s[e]][:]   (f32 accumulate)
__global__ __launch_bounds__(256) void k_agg(const uint8_t* __restrict__ featB, size_t strideB,
                                             float* __restrict__ outF,
                                             const int* __restrict__ rp,
                                             const uint2* __restrict__ cedge,
                                             const float* __restrict__ dinv, int N) {
    int node = blockIdx.x * 4 + (threadIdx.x >> 6);
    if (node >= N) return;
    int lane = threadIdx.x & 63;
    const uint32_t off = lane * 4;
    int beg = rp[node], end = rp[node + 1];
    float di = dinv[node];
    float w0 = di * di;
    uint32_t v0 = *(const uint32_t*)(featB + (size_t)node * strideB + off);
    float ax = bf_lo(v0) * w0, ay = bf_hi(v0) * w0;
    int e = beg;
    for (; e + 4 <= end; e += 4) {
        uint2 e0 = cedge[e], e1 = cedge[e + 1], e2 = cedge[e + 2], e3 = cedge[e + 3];
        float wa = __uint_as_float(e0.y), wb = __uint_as_float(e1.y);
        float wc = __uint_as_float(e2.y), wd = __uint_as_float(e3.y);
        uint32_t g0 = *(const uint32_t*)(featB + (size_t)e0.x * strideB + off);
        uint32_t g1 = *(const uint32_t*)(featB + (size_t)e1.x * strideB + off);
        uint32_t g2 = *(const uint32_t*)(featB + (size_t)e2.x * strideB + off);
        uint32_t g3 = *(const uint32_t*)(featB + (size_t)e3.x * strideB + off);
        ax = fmaf(bf_lo(g0), wa, ax); ay = fmaf(bf_hi(g0), wa, ay);
        ax = fmaf(bf_lo(g1), wb, ax); ay = fmaf(bf_hi(g1), wb, ay);
        ax = fmaf(bf_lo(g2), wc, ax); ay = fmaf(bf_hi(g2), wc, ay);
        ax = fmaf(bf_lo(g3), wd, ax); ay = fmaf(bf_hi(g3), wd, ay);
    }
    for (; e < end; ++e) {
        uint2 e0 = cedge[e];
        float wa = __uint_as_float(e0.y);
        uint32_t g0 = *(const uint32_t*)(featB + (size_t)e0.x * strideB + off);
        ax = fmaf(bf_lo(g0), wa, ax); ay = fmaf(bf_hi(g0), wa, ay);
    }
    *(float2*)(outF + (size_t)node * 128 + lane * 2) = make_float2(ax, ay);
}

// -------------------- GEMM1: h = relu(F @ W + b), W staged as bf16 in LDS (32 KB) --------------------
// Lane tx reads its 8 weights as ONE contiguous ds_read_b128 at byte tx*16 -> 2-way bank
// aliasing (free). Epilogue writes h as packed bf16 in-row over F (wave-private rows).
__global__ __launch_bounds__(256) void k_gemm_relu_bf16(
        const float* __restrict__ F, uint8_t* __restrict__ HB,
        const float* __restrict__ W, const float* __restrict__ b, int nrows) {
    __shared__ uint32_t WsB[128 * 64];  // row k = 64 packed bf16-pairs (cols 2j, 2j+1)
    for (int t = threadIdx.x; t < 128 * 64; t += 256) {
        int k = t >> 6, j = t & 63;
        float2 w2 = *(const float2*)(W + k * 128 + j * 2);
        WsB[t] = pack_bf16(w2.x, w2.y);
    }
    __syncthreads();

    const int ty = threadIdx.x >> 4, tx = threadIdx.x & 15;
    const int r0 = blockIdx.x * 64 + ty * 4;
    const int c0 = tx * 8;

    float acc[4][8];
#pragma unroll
    for (int i = 0; i < 4; i++)
#pragma unroll
        for (int j = 0; j < 8; j++) acc[i][j] = 0.0f;

    for (int kb = 0; kb < 128; kb += 4) {
        float fk[4][4];
#pragma unroll
        for (int i = 0; i < 4; i++) {
            int r = r0 + i;
            float4 a = (r < nrows) ? *(const float4*)(F + (size_t)r * 128 + kb)
                                   : make_float4(0.f, 0.f, 0.f, 0.f);
            fk[i][0] = a.x; fk[i][1] = a.y; fk[i][2] = a.z; fk[i][3] = a.w;
        }
#pragma unroll
        for (int kk = 0; kk < 4; kk++) {
            const uint4 wp = *(const uint4*)(WsB + (kb + kk) * 64 + tx * 4);
            const float wv[8] = {bf_lo(wp.x), bf_hi(wp.x), bf_lo(wp.y), bf_hi(wp.y),
                                 bf_lo(wp.z), bf_hi(wp.z), bf_lo(wp.w), bf_hi(wp.w)};
#pragma unroll
            for (int i = 0; i < 4; i++) {
                const float f = fk[i][kk];
#pragma unroll
                for (int j = 0; j < 8; j++) acc[i][j] = fmaf(f, wv[j], acc[i][j]);
            }
        }
    }

    const float4 b0 = *(const float4*)(b + c0);
    const float4 b1v = *(const float4*)(b + c0 + 4);
    const float bb[8] = {b0.x, b0.y, b0.z, b0.w, b1v.x, b1v.y, b1v.z, b1v.w};
#pragma unroll
    for (int i = 0; i < 4; i++) {
        int r = r0 + i;
        if (r >= nrows) continue;
        float h[8];
#pragma unroll
        for (int j = 0; j < 8; j++) h[j] = fmaxf(acc[i][j] + bb[j], 0.f);
        uint4 p = make_uint4(pack_bf16(h[0], h[1]), pack_bf16(h[2], h[3]),
                             pack_bf16(h[4], h[5]), pack_bf16(h[6], h[7]));
        *(uint4*)(HB + (size_t)r * 512 + (size_t)c0 * 2) = p;
    }
}

// -------------------- GEMM2: out = G @ [Wmu | Wlv] + [bmu | blv], bf16-W LDS --------------------
__global__ __launch_bounds__(256) void k_gemm_out(
        const float* __restrict__ G,
        const float* __restrict__ Wmu, const float* __restrict__ Wlv,
        const float* __restrict__ bmu, const float* __restrict__ blv,
        float* __restrict__ out, int nrows) {
    __shared__ uint32_t WsB[128 * 64];  // row k = [Wmu[k][0..63] | Wlv[k][0..63]] packed
    for (int t = threadIdx.x; t < 128 * 64; t += 256) {
        int k = t >> 6, j = t & 63;
        float2 w2 = (j < 32) ? *(const float2*)(Wmu + k * 64 + j * 2)
                             : *(const float2*)(Wlv + k * 64 + (j - 32) * 2);
        WsB[t] = pack_bf16(w2.x, w2.y);
    }
    __syncthreads();

    const int ty = threadIdx.x >> 4, tx = threadIdx.x & 15;
    const int r0 = blockIdx.x * 64 + ty * 4;
    const int c0 = tx * 8;

    float acc[4][8];
#pragma unroll
    for (int i = 0; i < 4; i++)
#pragma unroll
        for (int j = 0; j < 8; j++) acc[i][j] = 0.0f;

    for (int kb = 0; kb < 128; kb += 4) {
        float fk[4][4];
#pragma unroll
        for (int i = 0; i < 4; i++) {
            int r = r0 + i;
            float4 a = (r < nrows) ? *(const float4*)(G + (size_t)r * 128 + kb)
                                   : make_float4(0.f, 0.f, 0.f, 0.f);
            fk[i][0] = a.x; fk[i][1] = a.y; fk[i][2] = a.z; fk[i][3] = a.w;
        }
#pragma unroll
        for (int kk = 0; kk < 4; kk++) {
            const uint4 wp = *(const uint4*)(WsB + (kb + kk) * 64 + tx * 4);
            const float wv[8] = {bf_lo(wp.x), bf_hi(wp.x), bf_lo(wp.y), bf_hi(wp.y),
                                 bf_lo(wp.z), bf_hi(wp.z), bf_lo(wp.w), bf_hi(wp.w)};
#pragma unroll
            for (int i = 0; i < 4; i++) {
                const float f = fk[i][kk];
#pragma unroll
                for (int j = 0; j < 8; j++) acc[i][j] = fmaf(f, wv[j], acc[i][j]);
            }
        }
    }

    const size_t lvoff = (size_t)nrows * 64;
    const float* bb = (c0 < 64) ? (bmu + c0) : (blv + (c0 - 64));
    float* obase    = (c0 < 64) ? out : (out + lvoff);
    const int oc    = (c0 < 64) ? c0 : (c0 - 64);
    const float4 b0 = *(const float4*)bb;
    const float4 b1v = *(const float4*)(bb + 4);
#pragma unroll
    for (int i = 0; i < 4; i++) {
        int r = r0 + i;
        if (r >= nrows) continue;
        float4 o0 = make_float4(acc[i][0] + b0.x, acc[i][1] + b0.y,
                                acc[i][2] + b0.z, acc[i][3] + b0.w);
        float4 o1 = make_float4(acc[i][4] + b1v.x, acc[i][5] + b1v.y,
                                acc[i][6] + b1v.z, acc[i][7] + b1v.w);
        *(float4*)(obase + (size_t)r * 64 + oc) = o0;
        *(float4*)(obase + (size_t)r * 64 + oc + 4) = o1;
    }
}

// -------------------- launcher --------------------
extern "C" void kernel_launch(void* const* d_in, const int* in_sizes, int n_in,
                              void* d_out, int out_size, void* d_ws, size_t ws_size,
                              hipStream_t stream) {
    const float* x   = (const float*)d_in[0];
    const int*   ei  = (const int*)d_in[1];
    const float* W1  = (const float*)d_in[2];
    const float* b1  = (const float*)d_in[3];
    const float* Wmu = (const float*)d_in[4];
    const float* bmu = (const float*)d_in[5];
    const float* Wlv = (const float*)d_in[6];
    const float* blv = (const float*)d_in[7];
    float* out = (float*)d_out;

    const int N = in_sizes[0] / 128;
    const int E = in_sizes[1] / 2;
    const int* src = ei;
    const int* dst = ei + E;

    // workspace (~66 MB)
    char* ws = (char*)d_ws;
    size_t off = 0;
    float* dinv = (float*)(ws + off); off = ws_align(off + (size_t)N * 4);
    int* cnt    = (int*)(ws + off);   off = ws_align(off + (size_t)N * 4);
    int* rp     = (int*)(ws + off);   off = ws_align(off + (size_t)(N + 1) * 4);
    int* fill   = (int*)(ws + off);   off = ws_align(off + (size_t)N * 4);
    int* bsum   = (int*)(ws + off);   off = ws_align(off + 1024 * 4);
    uint2* cedge = (uint2*)(ws + off); off = ws_align(off + (size_t)E * 8);
    float* G    = (float*)(ws + off); off = ws_align(off + (size_t)N * 512);
    // x-as-bf16 lives in G's buffer (dead until agg2 writes G)
    uint32_t* xb = (uint32_t*)G;             // N*128 bf16, row stride 256 B
    float* F = out;                          // agg1 output f32 (N*128 == out_size)
    uint8_t* HB = (uint8_t*)out;             // h as packed bf16, row stride 512 B

    const int b = 256;
    const int nbN = (N + b - 1) / b;
    const int nbE = (E + b - 1) / b;
    const int nscan = (N + 1023) / 1024;

    // ---- CSR build ----
    hipMemsetAsync(cnt, 0, (size_t)N * 4, stream);
    hipMemsetAsync(fill, 0, (size_t)N * 4, stream);
    k_hist<<<nbE, b, 0, stream>>>(dst, cnt, E);
    k_dinv<<<nbN, b, 0, stream>>>(cnt, dinv, N);
    k_scan1<<<nscan, 256, 0, stream>>>(cnt, rp, bsum, N);
    k_scan2<<<1, 256, 0, stream>>>(bsum, nscan);
    k_scan3<<<(N + 1 + b - 1) / b, b, 0, stream>>>(rp, bsum, N, E);
    k_fill<<<nbE, b, 0, stream>>>(src, dst, dinv, rp, fill, cedge, E);

    // ---- layer 1 ----
    k_cvt<<<(N * 32 + b - 1) / b, b, 0, stream>>>(x, xb, N * 32);
    const int aggBlocks = (N + 3) / 4;
    k_agg<<<aggBlocks, 256, 0, stream>>>((const uint8_t*)xb, 256, F, rp, cedge, dinv, N);
    k_gemm_relu_bf16<<<(N + 63) / 64, 256, 0, stream>>>(F, HB, W1, b1, N);

    // ---- layer 2 ----
    k_agg<<<aggBlocks, 256, 0, stream>>>(HB, 512, G, rp, cedge, dinv, N);
    k_gemm_out<<<(N + 63) / 64, 256, 0, stream>>>(G, Wmu, Wlv, bmu, blv, out, N);
}

// Round 5
// 361.993 us; speedup vs baseline: 8.1197x; 1.3523x over previous
//
#include <hip/hip_runtime.h>
#include <hip/hip_bf16.h>
#include <stdint.h>

static inline size_t ws_align(size_t x) { return (x + 255) & ~(size_t)255; }

typedef __attribute__((ext_vector_type(8))) short bf16x8;
typedef __attribute__((ext_vector_type(4))) float f32x4;

// RTNE f32 -> bf16 pair packed into uint32 (elem0 in low 16)
__device__ __forceinline__ uint32_t pack_bf16(float a, float b) {
    uint32_t ua = __float_as_uint(a), ub = __float_as_uint(b);
    ua = (ua + 0x7fffu + ((ua >> 16) & 1u)) >> 16;
    ub = (ub + 0x7fffu + ((ub >> 16) & 1u)) >> 16;
    return ua | (ub << 16);
}
__device__ __forceinline__ uint16_t cvt_bf16(float a) {
    uint32_t ua = __float_as_uint(a);
    return (uint16_t)((ua + 0x7fffu + ((ua >> 16) & 1u)) >> 16);
}
__device__ __forceinline__ float bf_lo(uint32_t v) { return __uint_as_float(v << 16); }
__device__ __forceinline__ float bf_hi(uint32_t v) { return __uint_as_float(v & 0xffff0000u); }

// -------------------- degree histogram --------------------
__global__ void k_hist(const int* __restrict__ dst, int* __restrict__ cnt, int E) {
    int e = blockIdx.x * blockDim.x + threadIdx.x;
    if (e < E) atomicAdd(&cnt[dst[e]], 1);
}

__global__ void k_dinv(const int* __restrict__ cnt, float* __restrict__ dinv, int N) {
    int i = blockIdx.x * blockDim.x + threadIdx.x;
    if (i < N) dinv[i] = rsqrtf((float)(cnt[i] + 1));
}

// -------------------- exclusive scan --------------------
__global__ __launch_bounds__(256) void k_scan1(const int* __restrict__ cnt, int* __restrict__ rp,
                                               int* __restrict__ bsum, int N) {
    __shared__ int sh[256];
    int t = threadIdx.x;
    int base = blockIdx.x * 1024 + t * 4;
    int v[4];
#pragma unroll
    for (int i = 0; i < 4; i++) v[i] = (base + i < N) ? cnt[base + i] : 0;
    int s = v[0] + v[1] + v[2] + v[3];
    sh[t] = s;
    __syncthreads();
    for (int off = 1; off < 256; off <<= 1) {
        int x = (t >= off) ? sh[t - off] : 0;
        __syncthreads();
        sh[t] += x;
        __syncthreads();
    }
    int excl = sh[t] - s;
    if (t == 255) bsum[blockIdx.x] = sh[255];
    int run = excl;
#pragma unroll
    for (int i = 0; i < 4; i++) {
        if (base + i < N) rp[base + i] = run;
        run += v[i];
    }
}

__global__ __launch_bounds__(256) void k_scan2(int* __restrict__ bsum, int nb) {
    __shared__ int sh[256];
    int t = threadIdx.x;
    int v = (t < nb) ? bsum[t] : 0;
    sh[t] = v;
    __syncthreads();
    for (int off = 1; off < 256; off <<= 1) {
        int x = (t >= off) ? sh[t - off] : 0;
        __syncthreads();
        sh[t] += x;
        __syncthreads();
    }
    if (t < nb) bsum[t] = sh[t] - v;
}

__global__ void k_scan3(int* __restrict__ rp, const int* __restrict__ bsum, int N, int E) {
    int i = blockIdx.x * blockDim.x + threadIdx.x;
    if (i < N) rp[i] += bsum[i >> 10];
    if (i == N) rp[N] = E;
}

// -------------------- CSR fill, XCD-partitioned by dst range --------------------
// Each edge-chunk is scanned by 8 blocks; block handles only dst in its 1/8 node range.
// With wg->XCD round-robin, each XCD's cedge writes stay in its own L2 slice (clean
// full-line writebacks) instead of random 8-B scatter across 12.8 MB. Correct under
// ANY wg->XCD mapping (every edge accepted by exactly one partition).
__global__ __launch_bounds__(256) void k_fill(const int* __restrict__ src, const int* __restrict__ dst,
                                              const float* __restrict__ dinv, const int* __restrict__ rp,
                                              int* __restrict__ fill, uint2* __restrict__ cedge,
                                              int E, int nchunk, int N) {
    const int part = blockIdx.x & 7;
    const int chunk = blockIdx.x >> 3;
    const int lo = (int)((size_t)N * part / 8);
    const int hi = (int)((size_t)N * (part + 1) / 8);
    const int per = (E + nchunk - 1) / nchunk;
    const int e1 = (chunk * per + per < E) ? chunk * per + per : E;
    for (int e = chunk * per + threadIdx.x; e < e1; e += 256) {
        int d = dst[e];
        if (d >= lo && d < hi) {
            int s = src[e];
            int pos = rp[d] + atomicAdd(&fill[d], 1);
            cedge[pos] = make_uint2((uint32_t)s, __float_as_uint(dinv[s] * dinv[d]));
        }
    }
}

// -------------------- f32 -> packed bf16 convert --------------------
__global__ void k_cvt(const float* __restrict__ in, uint32_t* __restrict__ outp, int n4) {
    int idx = blockIdx.x * blockDim.x + threadIdx.x;
    if (idx >= n4) return;
    float4 v = ((const float4*)in)[idx];
    ((uint2*)outp)[idx] = make_uint2(pack_bf16(v.x, v.y), pack_bf16(v.z, v.w));
}

// -------------------- aggregation: bf16 in, f32 accumulate, bf16 packed out --------------------
// outB[d][:] = bf16( dinv[d]^2 * feat[d][:] + sum_e w[e] * feat[s[e]][:] )
__global__ __launch_bounds__(256) void k_agg(const uint8_t* __restrict__ featB,
                                             uint32_t* __restrict__ outB,
                                             const int* __restrict__ rp,
                                             const uint2* __restrict__ cedge,
                                             const float* __restrict__ dinv, int N) {
    int node = blockIdx.x * 4 + (threadIdx.x >> 6);
    if (node >= N) return;
    int lane = threadIdx.x & 63;
    const uint32_t off = lane * 4;
    int beg = rp[node], end = rp[node + 1];
    float di = dinv[node];
    float w0 = di * di;
    uint32_t v0 = *(const uint32_t*)(featB + (size_t)node * 256 + off);
    float ax = bf_lo(v0) * w0, ay = bf_hi(v0) * w0;
    int e = beg;
    for (; e + 4 <= end; e += 4) {
        uint2 e0 = cedge[e], e1 = cedge[e + 1], e2 = cedge[e + 2], e3 = cedge[e + 3];
        float wa = __uint_as_float(e0.y), wb = __uint_as_float(e1.y);
        float wc = __uint_as_float(e2.y), wd = __uint_as_float(e3.y);
        uint32_t g0 = *(const uint32_t*)(featB + (size_t)e0.x * 256 + off);
        uint32_t g1 = *(const uint32_t*)(featB + (size_t)e1.x * 256 + off);
        uint32_t g2 = *(const uint32_t*)(featB + (size_t)e2.x * 256 + off);
        uint32_t g3 = *(const uint32_t*)(featB + (size_t)e3.x * 256 + off);
        ax = fmaf(bf_lo(g0), wa, ax); ay = fmaf(bf_hi(g0), wa, ay);
        ax = fmaf(bf_lo(g1), wb, ax); ay = fmaf(bf_hi(g1), wb, ay);
        ax = fmaf(bf_lo(g2), wc, ax); ay = fmaf(bf_hi(g2), wc, ay);
        ax = fmaf(bf_lo(g3), wd, ax); ay = fmaf(bf_hi(g3), wd, ay);
    }
    for (; e < end; ++e) {
        uint2 e0 = cedge[e];
        float wa = __uint_as_float(e0.y);
        uint32_t g0 = *(const uint32_t*)(featB + (size_t)e0.x * 256 + off);
        ax = fmaf(bf_lo(g0), wa, ax); ay = fmaf(bf_hi(g0), wa, ay);
    }
    outB[(size_t)node * 64 + lane] = pack_bf16(ax, ay);
}

// -------------------- MFMA GEMM1: C = bf16(relu(A @ W + b)), in-place over A --------------------
// A: [N][128] bf16 rows (256B). B^T staged in LDS bf16, row n stride 272B (even bank spread).
// mfma_f32_16x16x32_bf16: A-frag lane l: row l%16, k=(l/16)*8+j (contiguous, per m92/m97);
// C/D: col=l&15, row=(l>>4)*4+reg (m89). Wave w owns rows [b*64+16w, +16): reads them fully
// into regs before its stores -> in-place safe.
__global__ __launch_bounds__(256) void k_gemm1_mfma(
        const uint8_t* __restrict__ A, uint8_t* __restrict__ C,
        const float* __restrict__ W, const float* __restrict__ bias, int N) {
    __shared__ uint32_t Bt[128 * 68];  // B^T: [n][k-pairs], 272B row stride
    {
        int c = threadIdx.x & 127;
        for (int k2 = threadIdx.x >> 7; k2 < 64; k2 += 2)
            Bt[c * 68 + k2] = pack_bf16(W[(2 * k2) * 128 + c], W[(2 * k2 + 1) * 128 + c]);
    }
    __syncthreads();

    const int lane = threadIdx.x & 63;
    const int wv = threadIdx.x >> 6;
    const int rrow = lane & 15;
    const int g = lane >> 4;
    const int r0 = blockIdx.x * 64 + wv * 16;
    const int rl = r0 + rrow;
    const int rc = (rl < N) ? rl : (N - 1);

    bf16x8 a[4];
    const uint8_t* arow = A + (size_t)rc * 256 + g * 16;
#pragma unroll
    for (int kb = 0; kb < 4; kb++) a[kb] = *(const bf16x8*)(arow + kb * 64);

    f32x4 acc[8];
#pragma unroll
    for (int ct = 0; ct < 8; ct++) acc[ct] = (f32x4){0.f, 0.f, 0.f, 0.f};

    const char* btb = (const char*)Bt;
#pragma unroll
    for (int ct = 0; ct < 8; ct++) {
        const char* bp = btb + (ct * 16 + rrow) * 272 + g * 16;
#pragma unroll
        for (int kb = 0; kb < 4; kb++) {
            bf16x8 bfr = *(const bf16x8*)(bp + kb * 64);
            acc[ct] = __builtin_amdgcn_mfma_f32_16x16x32_bf16(a[kb], bfr, acc[ct], 0, 0, 0);
        }
    }

#pragma unroll
    for (int ct = 0; ct < 8; ct++) {
        const int col = ct * 16 + rrow;
        const float bv = bias[col];
#pragma unroll
        for (int r = 0; r < 4; r++) {
            int row = r0 + g * 4 + r;
            if (row < N) {
                float h = fmaxf(acc[ct][r] + bv, 0.f);
                *(uint16_t*)(C + (size_t)row * 256 + col * 2) = cvt_bf16(h);
            }
        }
    }
}

// -------------------- MFMA GEMM2: out = A @ [Wmu|Wlv] + [bmu|blv] (f32, split) --------------------
__global__ __launch_bounds__(256) void k_gemm2_mfma(
        const uint8_t* __restrict__ A, float* __restrict__ out,
        const float* __restrict__ Wmu, const float* __restrict__ Wlv,
        const float* __restrict__ bmu, const float* __restrict__ blv, int N) {
    __shared__ uint32_t Bt[128 * 68];
    {
        int c = threadIdx.x & 127;
        const float* Wc = (c < 64) ? (Wmu + c) : (Wlv + (c - 64));
        for (int k2 = threadIdx.x >> 7; k2 < 64; k2 += 2)
            Bt[c * 68 + k2] = pack_bf16(Wc[(2 * k2) * 64], Wc[(2 * k2 + 1) * 64]);
    }
    __syncthreads();

    const int lane = threadIdx.x & 63;
    const int wv = threadIdx.x >> 6;
    const int rrow = lane & 15;
    const int g = lane >> 4;
    const int r0 = blockIdx.x * 64 + wv * 16;
    const int rl = r0 + rrow;
    const int rc = (rl < N) ? rl : (N - 1);

    bf16x8 a[4];
    const uint8_t* arow = A + (size_t)rc * 256 + g * 16;
#pragma unroll
    for (int kb = 0; kb < 4; kb++) a[kb] = *(const bf16x8*)(arow + kb * 64);

    f32x4 acc[8];
#pragma unroll
    for (int ct = 0; ct < 8; ct++) acc[ct] = (f32x4){0.f, 0.f, 0.f, 0.f};

    const char* btb = (const char*)Bt;
#pragma unroll
    for (int ct = 0; ct < 8; ct++) {
        const char* bp = btb + (ct * 16 + rrow) * 272 + g * 16;
#pragma unroll
        for (int kb = 0; kb < 4; kb++) {
            bf16x8 bfr = *(const bf16x8*)(bp + kb * 64);
            acc[ct] = __builtin_amdgcn_mfma_f32_16x16x32_bf16(a[kb], bfr, acc[ct], 0, 0, 0);
        }
    }

#pragma unroll
    for (int ct = 0; ct < 8; ct++) {
        const int col = ct * 16 + rrow;
        const float bv = (col < 64) ? bmu[col] : blv[col - 64];
        float* obase = (col < 64) ? (out + col) : (out + (size_t)N * 64 + (col - 64));
#pragma unroll
        for (int r = 0; r < 4; r++) {
            int row = r0 + g * 4 + r;
            if (row < N) obase[(size_t)row * 64] = acc[ct][r] + bv;
        }
    }
}

// -------------------- launcher --------------------
extern "C" void kernel_launch(void* const* d_in, const int* in_sizes, int n_in,
                              void* d_out, int out_size, void* d_ws, size_t ws_size,
                              hipStream_t stream) {
    const float* x   = (const float*)d_in[0];
    const int*   ei  = (const int*)d_in[1];
    const float* W1  = (const float*)d_in[2];
    const float* b1  = (const float*)d_in[3];
    const float* Wmu = (const float*)d_in[4];
    const float* bmu = (const float*)d_in[5];
    const float* Wlv = (const float*)d_in[6];
    const float* blv = (const float*)d_in[7];
    float* out = (float*)d_out;

    const int N = in_sizes[0] / 128;
    const int E = in_sizes[1] / 2;
    const int* src = ei;
    const int* dst = ei + E;

    // workspace (~66 MB)
    char* ws = (char*)d_ws;
    size_t off = 0;
    float* dinv  = (float*)(ws + off); off = ws_align(off + (size_t)N * 4);
    int* cnt     = (int*)(ws + off);   off = ws_align(off + (size_t)N * 4);
    int* rp      = (int*)(ws + off);   off = ws_align(off + (size_t)(N + 1) * 4);
    int* fill    = (int*)(ws + off);   off = ws_align(off + (size_t)N * 4);
    int* bsum    = (int*)(ws + off);   off = ws_align(off + 1024 * 4);
    uint2* cedge = (uint2*)(ws + off); off = ws_align(off + (size_t)E * 8);
    uint32_t* xb = (uint32_t*)(ws + off); off = ws_align(off + (size_t)N * 256);  // x~ / G2
    uint8_t* F1  = (uint8_t*)(ws + off);  off = ws_align(off + (size_t)N * 256);  // agg1 -> h (in-place)

    const int b = 256;
    const int nbN = (N + b - 1) / b;
    const int nbE = (E + b - 1) / b;
    const int nscan = (N + 1023) / 1024;

    // ---- CSR build ----
    hipMemsetAsync(cnt, 0, (size_t)N * 4, stream);
    hipMemsetAsync(fill, 0, (size_t)N * 4, stream);
    k_hist<<<nbE, b, 0, stream>>>(dst, cnt, E);
    k_dinv<<<nbN, b, 0, stream>>>(cnt, dinv, N);
    k_scan1<<<nscan, 256, 0, stream>>>(cnt, rp, bsum, N);
    k_scan2<<<1, 256, 0, stream>>>(bsum, nscan);
    k_scan3<<<(N + 1 + b - 1) / b, b, 0, stream>>>(rp, bsum, N, E);
    const int nchunk = 256;
    k_fill<<<nchunk * 8, 256, 0, stream>>>(src, dst, dinv, rp, fill, cedge, E, nchunk, N);

    // ---- layer 1 ----
    k_cvt<<<(N * 32 + b - 1) / b, b, 0, stream>>>(x, xb, N * 32);
    const int aggBlocks = (N + 3) / 4;
    k_agg<<<aggBlocks, 256, 0, stream>>>((const uint8_t*)xb, (uint32_t*)F1, rp, cedge, dinv, N);
    k_gemm1_mfma<<<(N + 63) / 64, 256, 0, stream>>>(F1, F1, W1, b1, N);

    // ---- layer 2 ----
    k_agg<<<aggBlocks, 256, 0, stream>>>(F1, xb, rp, cedge, dinv, N);
    k_gemm2_mfma<<<(N + 63) / 64, 256, 0, stream>>>((const uint8_t*)xb, out, Wmu, Wlv, bmu, blv, N);
}

// Round 6
// 266.356 us; speedup vs baseline: 11.0352x; 1.3591x over previous
//
#include <hip/hip_runtime.h>
#include <hip/hip_bf16.h>
#include <stdint.h>

static inline size_t ws_align(size_t x) { return (x + 255) & ~(size_t)255; }

typedef __attribute__((ext_vector_type(8))) short bf16x8;
typedef __attribute__((ext_vector_type(4))) float f32x4;

// RTNE f32 -> bf16 pair packed into uint32 (elem0 in low 16)
__device__ __forceinline__ uint32_t pack_bf16(float a, float b) {
    uint32_t ua = __float_as_uint(a), ub = __float_as_uint(b);
    ua = (ua + 0x7fffu + ((ua >> 16) & 1u)) >> 16;
    ub = (ub + 0x7fffu + ((ub >> 16) & 1u)) >> 16;
    return ua | (ub << 16);
}
__device__ __forceinline__ uint16_t cvt_bf16(float a) {
    uint32_t ua = __float_as_uint(a);
    return (uint16_t)((ua + 0x7fffu + ((ua >> 16) & 1u)) >> 16);
}
__device__ __forceinline__ float bf_lo(uint32_t v) { return __uint_as_float(v << 16); }
__device__ __forceinline__ float bf_hi(uint32_t v) { return __uint_as_float(v & 0xffff0000u); }

// ==================== bucket sort (no device-scope atomics anywhere) ====================
// Buckets of 256 consecutive dst nodes; NB = ceil(N/256) <= 512.

// Phase A: per (chunk, bucket) edge counts. LDS atomics only.
__global__ __launch_bounds__(256) void k_bcount(const int* __restrict__ dst, int* __restrict__ cntAB,
                                                int E, int nchunk, int NB) {
    __shared__ int h[512];
    for (int t = threadIdx.x; t < NB; t += 256) h[t] = 0;
    __syncthreads();
    const int c = blockIdx.x;
    const int per = (E + nchunk - 1) / nchunk;
    const int e0 = c * per, e1 = (e0 + per < E) ? e0 + per : E;
    for (int e = e0 + threadIdx.x; e < e1; e += 256)
        atomicAdd(&h[dst[e] >> 8], 1);
    __syncthreads();
    for (int t = threadIdx.x; t < NB; t += 256) cntAB[t * nchunk + c] = h[t];
}

// Phase B: scatter (src,dst) into bucket-grouped ebkt via LDS bump allocators.
__global__ __launch_bounds__(256) void k_bscatter(const int* __restrict__ src, const int* __restrict__ dst,
                                                  const int* __restrict__ baseAB, uint2* __restrict__ ebkt,
                                                  int E, int nchunk, int NB) {
    __shared__ int bump[512];
    const int c = blockIdx.x;
    for (int t = threadIdx.x; t < NB; t += 256) bump[t] = baseAB[t * nchunk + c];
    __syncthreads();
    const int per = (E + nchunk - 1) / nchunk;
    const int e0 = c * per, e1 = (e0 + per < E) ? e0 + per : E;
    for (int e = e0 + threadIdx.x; e < e1; e += 256) {
        int d = dst[e], s = src[e];
        int pos = atomicAdd(&bump[d >> 8], 1);
        ebkt[pos] = make_uint2((uint32_t)s, (uint32_t)d);
    }
}

// Phase C1: per-bucket dst histogram -> cnt[] (replaces device-atomic k_hist).
__global__ __launch_bounds__(256) void k_bhist(const uint2* __restrict__ ebkt, const int* __restrict__ baseAB,
                                               int* __restrict__ cnt, int nchunk, int N) {
    __shared__ int h[256];
    h[threadIdx.x] = 0;
    __syncthreads();
    const int b = blockIdx.x;
    const int e0 = baseAB[b * nchunk], e1 = baseAB[(b + 1) * nchunk];  // sentinel at [NB*nchunk] = E
    for (int e = e0 + threadIdx.x; e < e1; e += 256)
        atomicAdd(&h[ebkt[e].y & 255], 1);
    __syncthreads();
    int node = (b << 8) + threadIdx.x;
    if (node < N) cnt[node] = h[threadIdx.x];
}

// Phase C2: per-bucket placement via LDS fill counters -> cedge (src, weight).
__global__ __launch_bounds__(256) void k_bfill(const uint2* __restrict__ ebkt, const int* __restrict__ baseAB,
                                               const int* __restrict__ rp, const float* __restrict__ dinv,
                                               uint2* __restrict__ cedge, int nchunk) {
    __shared__ int fl[256];
    fl[threadIdx.x] = 0;
    __syncthreads();
    const int b = blockIdx.x;
    const int e0 = baseAB[b * nchunk], e1 = baseAB[(b + 1) * nchunk];
    for (int e = e0 + threadIdx.x; e < e1; e += 256) {
        uint2 sd = ebkt[e];
        int d = (int)sd.y;
        int posL = atomicAdd(&fl[d & 255], 1);
        cedge[rp[d] + posL] = make_uint2(sd.x, __float_as_uint(dinv[sd.x] * dinv[d]));
    }
}

__global__ void k_dinv(const int* __restrict__ cnt, float* __restrict__ dinv, int N) {
    int i = blockIdx.x * blockDim.x + threadIdx.x;
    if (i < N) dinv[i] = rsqrtf((float)(cnt[i] + 1));
}

// -------------------- exclusive scan --------------------
__global__ __launch_bounds__(256) void k_scan1(const int* __restrict__ cnt, int* __restrict__ rp,
                                               int* __restrict__ bsum, int N) {
    __shared__ int sh[256];
    int t = threadIdx.x;
    int base = blockIdx.x * 1024 + t * 4;
    int v[4];
#pragma unroll
    for (int i = 0; i < 4; i++) v[i] = (base + i < N) ? cnt[base + i] : 0;
    int s = v[0] + v[1] + v[2] + v[3];
    sh[t] = s;
    __syncthreads();
    for (int off = 1; off < 256; off <<= 1) {
        int x = (t >= off) ? sh[t - off] : 0;
        __syncthreads();
        sh[t] += x;
        __syncthreads();
    }
    int excl = sh[t] - s;
    if (t == 255) bsum[blockIdx.x] = sh[255];
    int run = excl;
#pragma unroll
    for (int i = 0; i < 4; i++) {
        if (base + i < N) rp[base + i] = run;
        run += v[i];
    }
}

__global__ __launch_bounds__(256) void k_scan2(int* __restrict__ bsum, int nb) {
    __shared__ int sh[256];
    int t = threadIdx.x;
    int v = (t < nb) ? bsum[t] : 0;
    sh[t] = v;
    __syncthreads();
    for (int off = 1; off < 256; off <<= 1) {
        int x = (t >= off) ? sh[t - off] : 0;
        __syncthreads();
        sh[t] += x;
        __syncthreads();
    }
    if (t < nb) bsum[t] = sh[t] - v;
}

__global__ void k_scan3(int* __restrict__ rp, const int* __restrict__ bsum, int N, int E) {
    int i = blockIdx.x * blockDim.x + threadIdx.x;
    if (i < N) rp[i] += bsum[i >> 10];
    if (i == N) rp[N] = E;  // sentinel
}

// -------------------- f32 -> packed bf16 convert --------------------
__global__ void k_cvt(const float* __restrict__ in, uint32_t* __restrict__ outp, int n4) {
    int idx = blockIdx.x * blockDim.x + threadIdx.x;
    if (idx >= n4) return;
    float4 v = ((const float4*)in)[idx];
    ((uint2*)outp)[idx] = make_uint2(pack_bf16(v.x, v.y), pack_bf16(v.z, v.w));
}

// -------------------- aggregation: bf16 in, f32 accumulate, bf16 packed out --------------------
__global__ __launch_bounds__(256) void k_agg(const uint8_t* __restrict__ featB,
                                             uint32_t* __restrict__ outB,
                                             const int* __restrict__ rp,
                                             const uint2* __restrict__ cedge,
                                             const float* __restrict__ dinv, int N) {
    int node = blockIdx.x * 4 + (threadIdx.x >> 6);
    if (node >= N) return;
    int lane = threadIdx.x & 63;
    const uint32_t off = lane * 4;
    int beg = rp[node], end = rp[node + 1];
    float di = dinv[node];
    float w0 = di * di;
    uint32_t v0 = *(const uint32_t*)(featB + (size_t)node * 256 + off);
    float ax = bf_lo(v0) * w0, ay = bf_hi(v0) * w0;
    int e = beg;
    for (; e + 4 <= end; e += 4) {
        uint2 e0 = cedge[e], e1 = cedge[e + 1], e2 = cedge[e + 2], e3 = cedge[e + 3];
        float wa = __uint_as_float(e0.y), wb = __uint_as_float(e1.y);
        float wc = __uint_as_float(e2.y), wd = __uint_as_float(e3.y);
        uint32_t g0 = *(const uint32_t*)(featB + (size_t)e0.x * 256 + off);
        uint32_t g1 = *(const uint32_t*)(featB + (size_t)e1.x * 256 + off);
        uint32_t g2 = *(const uint32_t*)(featB + (size_t)e2.x * 256 + off);
        uint32_t g3 = *(const uint32_t*)(featB + (size_t)e3.x * 256 + off);
        ax = fmaf(bf_lo(g0), wa, ax); ay = fmaf(bf_hi(g0), wa, ay);
        ax = fmaf(bf_lo(g1), wb, ax); ay = fmaf(bf_hi(g1), wb, ay);
        ax = fmaf(bf_lo(g2), wc, ax); ay = fmaf(bf_hi(g2), wc, ay);
        ax = fmaf(bf_lo(g3), wd, ax); ay = fmaf(bf_hi(g3), wd, ay);
    }
    for (; e < end; ++e) {
        uint2 e0 = cedge[e];
        float wa = __uint_as_float(e0.y);
        uint32_t g0 = *(const uint32_t*)(featB + (size_t)e0.x * 256 + off);
        ax = fmaf(bf_lo(g0), wa, ax); ay = fmaf(bf_hi(g0), wa, ay);
    }
    outB[(size_t)node * 64 + lane] = pack_bf16(ax, ay);
}

// -------------------- MFMA GEMM1: C = bf16(relu(A @ W + b)), in-place over A --------------------
__global__ __launch_bounds__(256) void k_gemm1_mfma(
        const uint8_t* __restrict__ A, uint8_t* __restrict__ C,
        const float* __restrict__ W, const float* __restrict__ bias, int N) {
    __shared__ uint32_t Bt[128 * 68];  // B^T: [n][k-pairs], 272B row stride
    {
        int c = threadIdx.x & 127;
        for (int k2 = threadIdx.x >> 7; k2 < 64; k2 += 2)
            Bt[c * 68 + k2] = pack_bf16(W[(2 * k2) * 128 + c], W[(2 * k2 + 1) * 128 + c]);
    }
    __syncthreads();

    const int lane = threadIdx.x & 63;
    const int wv = threadIdx.x >> 6;
    const int rrow = lane & 15;
    const int g = lane >> 4;
    const int r0 = blockIdx.x * 64 + wv * 16;
    const int rl = r0 + rrow;
    const int rc = (rl < N) ? rl : (N - 1);

    bf16x8 a[4];
    const uint8_t* arow = A + (size_t)rc * 256 + g * 16;
#pragma unroll
    for (int kb = 0; kb < 4; kb++) a[kb] = *(const bf16x8*)(arow + kb * 64);

    f32x4 acc[8];
#pragma unroll
    for (int ct = 0; ct < 8; ct++) acc[ct] = (f32x4){0.f, 0.f, 0.f, 0.f};

    const char* btb = (const char*)Bt;
#pragma unroll
    for (int ct = 0; ct < 8; ct++) {
        const char* bp = btb + (ct * 16 + rrow) * 272 + g * 16;
#pragma unroll
        for (int kb = 0; kb < 4; kb++) {
            bf16x8 bfr = *(const bf16x8*)(bp + kb * 64);
            acc[ct] = __builtin_amdgcn_mfma_f32_16x16x32_bf16(a[kb], bfr, acc[ct], 0, 0, 0);
        }
    }

#pragma unroll
    for (int ct = 0; ct < 8; ct++) {
        const int col = ct * 16 + rrow;
        const float bv = bias[col];
#pragma unroll
        for (int r = 0; r < 4; r++) {
            int row = r0 + g * 4 + r;
            if (row < N) {
                float h = fmaxf(acc[ct][r] + bv, 0.f);
                *(uint16_t*)(C + (size_t)row * 256 + col * 2) = cvt_bf16(h);
            }
        }
    }
}

// -------------------- MFMA GEMM2: out = A @ [Wmu|Wlv] + [bmu|blv] (f32, split) --------------------
__global__ __launch_bounds__(256) void k_gemm2_mfma(
        const uint8_t* __restrict__ A, float* __restrict__ out,
        const float* __restrict__ Wmu, const float* __restrict__ Wlv,
        const float* __restrict__ bmu, const float* __restrict__ blv, int N) {
    __shared__ uint32_t Bt[128 * 68];
    {
        int c = threadIdx.x & 127;
        const float* Wc = (c < 64) ? (Wmu + c) : (Wlv + (c - 64));
        for (int k2 = threadIdx.x >> 7; k2 < 64; k2 += 2)
            Bt[c * 68 + k2] = pack_bf16(Wc[(2 * k2) * 64], Wc[(2 * k2 + 1) * 64]);
    }
    __syncthreads();

    const int lane = threadIdx.x & 63;
    const int wv = threadIdx.x >> 6;
    const int rrow = lane & 15;
    const int g = lane >> 4;
    const int r0 = blockIdx.x * 64 + wv * 16;
    const int rl = r0 + rrow;
    const int rc = (rl < N) ? rl : (N - 1);

    bf16x8 a[4];
    const uint8_t* arow = A + (size_t)rc * 256 + g * 16;
#pragma unroll
    for (int kb = 0; kb < 4; kb++) a[kb] = *(const bf16x8*)(arow + kb * 64);

    f32x4 acc[8];
#pragma unroll
    for (int ct = 0; ct < 8; ct++) acc[ct] = (f32x4){0.f, 0.f, 0.f, 0.f};

    const char* btb = (const char*)Bt;
#pragma unroll
    for (int ct = 0; ct < 8; ct++) {
        const char* bp = btb + (ct * 16 + rrow) * 272 + g * 16;
#pragma unroll
        for (int kb = 0; kb < 4; kb++) {
            bf16x8 bfr = *(const bf16x8*)(bp + kb * 64);
            acc[ct] = __builtin_amdgcn_mfma_f32_16x16x32_bf16(a[kb], bfr, acc[ct], 0, 0, 0);
        }
    }

#pragma unroll
    for (int ct = 0; ct < 8; ct++) {
        const int col = ct * 16 + rrow;
        const float bv = (col < 64) ? bmu[col] : blv[col - 64];
        float* obase = (col < 64) ? (out + col) : (out + (size_t)N * 64 + (col - 64));
#pragma unroll
        for (int r = 0; r < 4; r++) {
            int row = r0 + g * 4 + r;
            if (row < N) obase[(size_t)row * 64] = acc[ct][r] + bv;
        }
    }
}

// -------------------- launcher --------------------
extern "C" void kernel_launch(void* const* d_in, const int* in_sizes, int n_in,
                              void* d_out, int out_size, void* d_ws, size_t ws_size,
                              hipStream_t stream) {
    const float* x   = (const float*)d_in[0];
    const int*   ei  = (const int*)d_in[1];
    const float* W1  = (const float*)d_in[2];
    const float* b1  = (const float*)d_in[3];
    const float* Wmu = (const float*)d_in[4];
    const float* bmu = (const float*)d_in[5];
    const float* Wlv = (const float*)d_in[6];
    const float* blv = (const float*)d_in[7];
    float* out = (float*)d_out;

    const int N = in_sizes[0] / 128;
    const int E = in_sizes[1] / 2;
    const int* src = ei;
    const int* dst = ei + E;

    const int nchunk = 256;
    const int NB = (N + 255) >> 8;           // buckets of 256 nodes (NB <= 512 for N <= 131072)
    const int M = NB * nchunk;               // cntAB / baseAB element count

    // workspace (~66 MB)
    char* ws = (char*)d_ws;
    size_t off = 0;
    float* dinv   = (float*)(ws + off); off = ws_align(off + (size_t)N * 4);
    int* cnt      = (int*)(ws + off);   off = ws_align(off + (size_t)N * 4);
    int* rp       = (int*)(ws + off);   off = ws_align(off + (size_t)(N + 1) * 4);
    int* bsum     = (int*)(ws + off);   off = ws_align(off + 1024 * 4);
    int* cntAB    = (int*)(ws + off);   off = ws_align(off + (size_t)(M + 64) * 4);
    int* baseAB   = (int*)(ws + off);   off = ws_align(off + (size_t)(M + 64) * 4);
    uint2* cedge  = (uint2*)(ws + off); off = ws_align(off + (size_t)E * 8);
    uint32_t* xb  = (uint32_t*)(ws + off); off = ws_align(off + (size_t)N * 256);  // x~ / G2
    uint8_t* F1   = (uint8_t*)(ws + off);  off = ws_align(off + (size_t)N * 256);  // agg1 -> h
    uint2* ebkt   = (uint2*)xb;  // aliases xb: dead before k_cvt writes xb (E*8 <= N*256)

    const int b = 256;
    const int nbN = (N + b - 1) / b;

    // ---- bucket-sorted CSR build: zero device-scope atomics ----
    k_bcount<<<nchunk, 256, 0, stream>>>(dst, cntAB, E, nchunk, NB);
    k_scan1<<<(M + 1023) / 1024, 256, 0, stream>>>(cntAB, baseAB, bsum, M);
    k_scan2<<<1, 256, 0, stream>>>(bsum, (M + 1023) / 1024);
    k_scan3<<<(M + 1 + b - 1) / b, b, 0, stream>>>(baseAB, bsum, M, E);   // baseAB[M] = E sentinel
    k_bscatter<<<nchunk, 256, 0, stream>>>(src, dst, baseAB, ebkt, E, nchunk, NB);
    k_bhist<<<NB, 256, 0, stream>>>(ebkt, baseAB, cnt, nchunk, N);
    k_dinv<<<nbN, b, 0, stream>>>(cnt, dinv, N);
    k_scan1<<<(N + 1023) / 1024, 256, 0, stream>>>(cnt, rp, bsum, N);
    k_scan2<<<1, 256, 0, stream>>>(bsum, (N + 1023) / 1024);
    k_scan3<<<(N + 1 + b - 1) / b, b, 0, stream>>>(rp, bsum, N, E);       // rp[N] = E
    k_bfill<<<NB, 256, 0, stream>>>(ebkt, baseAB, rp, dinv, cedge, nchunk);

    // ---- layer 1 ----
    k_cvt<<<(N * 32 + b - 1) / b, b, 0, stream>>>(x, xb, N * 32);
    const int aggBlocks = (N + 3) / 4;
    k_agg<<<aggBlocks, 256, 0, stream>>>((const uint8_t*)xb, (uint32_t*)F1, rp, cedge, dinv, N);
    k_gemm1_mfma<<<(N + 63) / 64, 256, 0, stream>>>(F1, F1, W1, b1, N);

    // ---- layer 2 ----
    k_agg<<<aggBlocks, 256, 0, stream>>>(F1, xb, rp, cedge, dinv, N);
    k_gemm2_mfma<<<(N + 63) / 64, 256, 0, stream>>>((const uint8_t*)xb, out, Wmu, Wlv, bmu, blv, N);
}

// Round 7
// 245.753 us; speedup vs baseline: 11.9603x; 1.0838x over previous
//
#include <hip/hip_runtime.h>
#include <hip/hip_bf16.h>
#include <stdint.h>

static inline size_t ws_align(size_t x) { return (x + 255) & ~(size_t)255; }

typedef __attribute__((ext_vector_type(8))) short bf16x8;
typedef __attribute__((ext_vector_type(4))) float f32x4;

// RTNE f32 -> bf16 pair packed into uint32 (elem0 in low 16)
__device__ __forceinline__ uint32_t pack_bf16(float a, float b) {
    uint32_t ua = __float_as_uint(a), ub = __float_as_uint(b);
    ua = (ua + 0x7fffu + ((ua >> 16) & 1u)) >> 16;
    ub = (ub + 0x7fffu + ((ub >> 16) & 1u)) >> 16;
    return ua | (ub << 16);
}
__device__ __forceinline__ uint16_t cvt_bf16(float a) {
    uint32_t ua = __float_as_uint(a);
    return (uint16_t)((ua + 0x7fffu + ((ua >> 16) & 1u)) >> 16);
}
__device__ __forceinline__ float bf_lo(uint32_t v) { return __uint_as_float(v << 16); }
__device__ __forceinline__ float bf_hi(uint32_t v) { return __uint_as_float(v & 0xffff0000u); }

// ==================== bucket sort (no device-scope atomics anywhere) ====================

// Phase A: per (chunk, bucket) edge counts. LDS atomics only.
__global__ __launch_bounds__(256) void k_bcount(const int* __restrict__ dst, int* __restrict__ cntAB,
                                                int E, int nchunk, int NB) {
    __shared__ int h[512];
    for (int t = threadIdx.x; t < NB; t += 256) h[t] = 0;
    __syncthreads();
    const int c = blockIdx.x;
    const int per = (E + nchunk - 1) / nchunk;
    const int e0 = c * per, e1 = (e0 + per < E) ? e0 + per : E;
    for (int e = e0 + threadIdx.x; e < e1; e += 256)
        atomicAdd(&h[dst[e] >> 8], 1);
    __syncthreads();
    for (int t = threadIdx.x; t < NB; t += 256) cntAB[t * nchunk + c] = h[t];
}

// Phase B: scatter (src,dst) into bucket-grouped ebkt via LDS bump allocators.
__global__ __launch_bounds__(256) void k_bscatter(const int* __restrict__ src, const int* __restrict__ dst,
                                                  const int* __restrict__ baseAB, uint2* __restrict__ ebkt,
                                                  int E, int nchunk, int NB) {
    __shared__ int bump[512];
    const int c = blockIdx.x;
    for (int t = threadIdx.x; t < NB; t += 256) bump[t] = baseAB[t * nchunk + c];
    __syncthreads();
    const int per = (E + nchunk - 1) / nchunk;
    const int e0 = c * per, e1 = (e0 + per < E) ? e0 + per : E;
    for (int e = e0 + threadIdx.x; e < e1; e += 256) {
        int d = dst[e], s = src[e];
        int pos = atomicAdd(&bump[d >> 8], 1);
        ebkt[pos] = make_uint2((uint32_t)s, (uint32_t)d);
    }
}

// Phase C1: per-bucket dst histogram -> cnt[] and dinv[] (fused).
__global__ __launch_bounds__(256) void k_bhist(const uint2* __restrict__ ebkt, const int* __restrict__ baseAB,
                                               int* __restrict__ cnt, float* __restrict__ dinv,
                                               int nchunk, int N) {
    __shared__ int h[256];
    h[threadIdx.x] = 0;
    __syncthreads();
    const int b = blockIdx.x;
    const int e0 = baseAB[b * nchunk], e1 = baseAB[(b + 1) * nchunk];  // sentinel at [NB*nchunk] = E
    for (int e = e0 + threadIdx.x; e < e1; e += 256)
        atomicAdd(&h[ebkt[e].y & 255], 1);
    __syncthreads();
    int node = (b << 8) + threadIdx.x;
    if (node < N) {
        int c = h[threadIdx.x];
        cnt[node] = c;
        dinv[node] = rsqrtf((float)(c + 1));
    }
}

// Phase C2: per-bucket placement via LDS fill counters -> cedge (src, weight).
__global__ __launch_bounds__(256) void k_bfill(const uint2* __restrict__ ebkt, const int* __restrict__ baseAB,
                                               const int* __restrict__ rp, const float* __restrict__ dinv,
                                               uint2* __restrict__ cedge, int nchunk) {
    __shared__ int fl[256];
    fl[threadIdx.x] = 0;
    __syncthreads();
    const int b = blockIdx.x;
    const int e0 = baseAB[b * nchunk], e1 = baseAB[(b + 1) * nchunk];
    for (int e = e0 + threadIdx.x; e < e1; e += 256) {
        uint2 sd = ebkt[e];
        int d = (int)sd.y;
        int posL = atomicAdd(&fl[d & 255], 1);
        cedge[rp[d] + posL] = make_uint2(sd.x, __float_as_uint(dinv[sd.x] * dinv[d]));
    }
}

// -------------------- exclusive scan --------------------
__global__ __launch_bounds__(256) void k_scan1(const int* __restrict__ cnt, int* __restrict__ rp,
                                               int* __restrict__ bsum, int N) {
    __shared__ int sh[256];
    int t = threadIdx.x;
    int base = blockIdx.x * 1024 + t * 4;
    int v[4];
#pragma unroll
    for (int i = 0; i < 4; i++) v[i] = (base + i < N) ? cnt[base + i] : 0;
    int s = v[0] + v[1] + v[2] + v[3];
    sh[t] = s;
    __syncthreads();
    for (int off = 1; off < 256; off <<= 1) {
        int x = (t >= off) ? sh[t - off] : 0;
        __syncthreads();
        sh[t] += x;
        __syncthreads();
    }
    int excl = sh[t] - s;
    if (t == 255) bsum[blockIdx.x] = sh[255];
    int run = excl;
#pragma unroll
    for (int i = 0; i < 4; i++) {
        if (base + i < N) rp[base + i] = run;
        run += v[i];
    }
}

__global__ __launch_bounds__(256) void k_scan2(int* __restrict__ bsum, int nb) {
    __shared__ int sh[256];
    int t = threadIdx.x;
    int v = (t < nb) ? bsum[t] : 0;
    sh[t] = v;
    __syncthreads();
    for (int off = 1; off < 256; off <<= 1) {
        int x = (t >= off) ? sh[t - off] : 0;
        __syncthreads();
        sh[t] += x;
        __syncthreads();
    }
    if (t < nb) bsum[t] = sh[t] - v;
}

__global__ void k_scan3(int* __restrict__ rp, const int* __restrict__ bsum, int N, int E) {
    int i = blockIdx.x * blockDim.x + threadIdx.x;
    if (i < N) rp[i] += bsum[i >> 10];
    if (i == N) rp[N] = E;  // sentinel
}

// -------------------- f32 -> packed bf16 convert --------------------
__global__ void k_cvt(const float* __restrict__ in, uint32_t* __restrict__ outp, int n4) {
    int idx = blockIdx.x * blockDim.x + threadIdx.x;
    if (idx >= n4) return;
    float4 v = ((const float4*)in)[idx];
    ((uint2*)outp)[idx] = make_uint2(pack_bf16(v.x, v.y), pack_bf16(v.z, v.w));
}

// -------------------- aggregation: wide-gather edition --------------------
// Wave = 1 node. Lane = (quarter q = lane>>4, col-oct j = lane&15).
// Lane gathers 16 B (cols 8j..8j+7) of quarter-q's edge rows; quarters process edges
// beg+q, beg+q+4, ... concurrently -> 4 edges (4x16B x 16 lanes = 4 rows) in flight per
// vmem instr group. Quarter-reduce via shfl_xor(16,32); q0 writes the 256-B row.
__global__ __launch_bounds__(256) void k_agg(const uint8_t* __restrict__ featB,
                                             uint32_t* __restrict__ outB,
                                             const int* __restrict__ rp,
                                             const uint2* __restrict__ cedge,
                                             const float* __restrict__ dinv, int N) {
    int node = blockIdx.x * 4 + (threadIdx.x >> 6);
    if (node >= N) return;
    int lane = threadIdx.x & 63;
    int j = lane & 15;   // 16-B col-oct
    int q = lane >> 4;   // edge phase
    int beg = rp[node], end = rp[node + 1];
    float di = dinv[node];
    float w0 = (q == 0) ? di * di : 0.0f;

    uint4 sv = *(const uint4*)(featB + (size_t)node * 256 + j * 16);
    float acc[8];
    acc[0] = bf_lo(sv.x) * w0; acc[1] = bf_hi(sv.x) * w0;
    acc[2] = bf_lo(sv.y) * w0; acc[3] = bf_hi(sv.y) * w0;
    acc[4] = bf_lo(sv.z) * w0; acc[5] = bf_hi(sv.z) * w0;
    acc[6] = bf_lo(sv.w) * w0; acc[7] = bf_hi(sv.w) * w0;

    int i = beg + q;
    for (; i + 4 < end; i += 8) {  // 2 edges per lane per iteration (this quarter's stream)
        uint2 ea = cedge[i], eb = cedge[i + 4];
        float wa = __uint_as_float(ea.y), wb = __uint_as_float(eb.y);
        uint4 ga = *(const uint4*)(featB + (size_t)ea.x * 256 + j * 16);
        uint4 gb = *(const uint4*)(featB + (size_t)eb.x * 256 + j * 16);
        acc[0] = fmaf(bf_lo(ga.x), wa, acc[0]); acc[1] = fmaf(bf_hi(ga.x), wa, acc[1]);
        acc[2] = fmaf(bf_lo(ga.y), wa, acc[2]); acc[3] = fmaf(bf_hi(ga.y), wa, acc[3]);
        acc[4] = fmaf(bf_lo(ga.z), wa, acc[4]); acc[5] = fmaf(bf_hi(ga.z), wa, acc[5]);
        acc[6] = fmaf(bf_lo(ga.w), wa, acc[6]); acc[7] = fmaf(bf_hi(ga.w), wa, acc[7]);
        acc[0] = fmaf(bf_lo(gb.x), wb, acc[0]); acc[1] = fmaf(bf_hi(gb.x), wb, acc[1]);
        acc[2] = fmaf(bf_lo(gb.y), wb, acc[2]); acc[3] = fmaf(bf_hi(gb.y), wb, acc[3]);
        acc[4] = fmaf(bf_lo(gb.z), wb, acc[4]); acc[5] = fmaf(bf_hi(gb.z), wb, acc[5]);
        acc[6] = fmaf(bf_lo(gb.w), wb, acc[6]); acc[7] = fmaf(bf_hi(gb.w), wb, acc[7]);
    }
    for (; i < end; i += 4) {
        uint2 ea = cedge[i];
        float wa = __uint_as_float(ea.y);
        uint4 ga = *(const uint4*)(featB + (size_t)ea.x * 256 + j * 16);
        acc[0] = fmaf(bf_lo(ga.x), wa, acc[0]); acc[1] = fmaf(bf_hi(ga.x), wa, acc[1]);
        acc[2] = fmaf(bf_lo(ga.y), wa, acc[2]); acc[3] = fmaf(bf_hi(ga.y), wa, acc[3]);
        acc[4] = fmaf(bf_lo(ga.z), wa, acc[4]); acc[5] = fmaf(bf_hi(ga.z), wa, acc[5]);
        acc[6] = fmaf(bf_lo(ga.w), wa, acc[6]); acc[7] = fmaf(bf_hi(ga.w), wa, acc[7]);
    }

#pragma unroll
    for (int k = 0; k < 8; k++) {
        acc[k] += __shfl_xor(acc[k], 16, 64);
        acc[k] += __shfl_xor(acc[k], 32, 64);
    }
    if (q == 0) {
        uint4 p = make_uint4(pack_bf16(acc[0], acc[1]), pack_bf16(acc[2], acc[3]),
                             pack_bf16(acc[4], acc[5]), pack_bf16(acc[6], acc[7]));
        *(uint4*)(outB + (size_t)node * 64 + j * 4) = p;
    }
}

// -------------------- MFMA GEMM1: C = bf16(relu(A @ W + b)), in-place over A --------------------
__global__ __launch_bounds__(256) void k_gemm1_mfma(
        const uint8_t* __restrict__ A, uint8_t* __restrict__ C,
        const float* __restrict__ W, const float* __restrict__ bias, int N) {
    __shared__ uint32_t Bt[128 * 68];  // B^T: [n][k-pairs], 272B row stride
    {
        int c = threadIdx.x & 127;
        for (int k2 = threadIdx.x >> 7; k2 < 64; k2 += 2)
            Bt[c * 68 + k2] = pack_bf16(W[(2 * k2) * 128 + c], W[(2 * k2 + 1) * 128 + c]);
    }
    __syncthreads();

    const int lane = threadIdx.x & 63;
    const int wv = threadIdx.x >> 6;
    const int rrow = lane & 15;
    const int g = lane >> 4;
    const int r0 = blockIdx.x * 64 + wv * 16;
    const int rl = r0 + rrow;
    const int rc = (rl < N) ? rl : (N - 1);

    bf16x8 a[4];
    const uint8_t* arow = A + (size_t)rc * 256 + g * 16;
#pragma unroll
    for (int kb = 0; kb < 4; kb++) a[kb] = *(const bf16x8*)(arow + kb * 64);

    f32x4 acc[8];
#pragma unroll
    for (int ct = 0; ct < 8; ct++) acc[ct] = (f32x4){0.f, 0.f, 0.f, 0.f};

    const char* btb = (const char*)Bt;
#pragma unroll
    for (int ct = 0; ct < 8; ct++) {
        const char* bp = btb + (ct * 16 + rrow) * 272 + g * 16;
#pragma unroll
        for (int kb = 0; kb < 4; kb++) {
            bf16x8 bfr = *(const bf16x8*)(bp + kb * 64);
            acc[ct] = __builtin_amdgcn_mfma_f32_16x16x32_bf16(a[kb], bfr, acc[ct], 0, 0, 0);
        }
    }

#pragma unroll
    for (int ct = 0; ct < 8; ct++) {
        const int col = ct * 16 + rrow;
        const float bv = bias[col];
#pragma unroll
        for (int r = 0; r < 4; r++) {
            int row = r0 + g * 4 + r;
            if (row < N) {
                float h = fmaxf(acc[ct][r] + bv, 0.f);
                *(uint16_t*)(C + (size_t)row * 256 + col * 2) = cvt_bf16(h);
            }
        }
    }
}

// -------------------- MFMA GEMM2: out = A @ [Wmu|Wlv] + [bmu|blv] (f32, split) --------------------
__global__ __launch_bounds__(256) void k_gemm2_mfma(
        const uint8_t* __restrict__ A, float* __restrict__ out,
        const float* __restrict__ Wmu, const float* __restrict__ Wlv,
        const float* __restrict__ bmu, const float* __restrict__ blv, int N) {
    __shared__ uint32_t Bt[128 * 68];
    {
        int c = threadIdx.x & 127;
        const float* Wc = (c < 64) ? (Wmu + c) : (Wlv + (c - 64));
        for (int k2 = threadIdx.x >> 7; k2 < 64; k2 += 2)
            Bt[c * 68 + k2] = pack_bf16(Wc[(2 * k2) * 64], Wc[(2 * k2 + 1) * 64]);
    }
    __syncthreads();

    const int lane = threadIdx.x & 63;
    const int wv = threadIdx.x >> 6;
    const int rrow = lane & 15;
    const int g = lane >> 4;
    const int r0 = blockIdx.x * 64 + wv * 16;
    const int rl = r0 + rrow;
    const int rc = (rl < N) ? rl : (N - 1);

    bf16x8 a[4];
    const uint8_t* arow = A + (size_t)rc * 256 + g * 16;
#pragma unroll
    for (int kb = 0; kb < 4; kb++) a[kb] = *(const bf16x8*)(arow + kb * 64);

    f32x4 acc[8];
#pragma unroll
    for (int ct = 0; ct < 8; ct++) acc[ct] = (f32x4){0.f, 0.f, 0.f, 0.f};

    const char* btb = (const char*)Bt;
#pragma unroll
    for (int ct = 0; ct < 8; ct++) {
        const char* bp = btb + (ct * 16 + rrow) * 272 + g * 16;
#pragma unroll
        for (int kb = 0; kb < 4; kb++) {
            bf16x8 bfr = *(const bf16x8*)(bp + kb * 64);
            acc[ct] = __builtin_amdgcn_mfma_f32_16x16x32_bf16(a[kb], bfr, acc[ct], 0, 0, 0);
        }
    }

#pragma unroll
    for (int ct = 0; ct < 8; ct++) {
        const int col = ct * 16 + rrow;
        const float bv = (col < 64) ? bmu[col] : blv[col - 64];
        float* obase = (col < 64) ? (out + col) : (out + (size_t)N * 64 + (col - 64));
#pragma unroll
        for (int r = 0; r < 4; r++) {
            int row = r0 + g * 4 + r;
            if (row < N) obase[(size_t)row * 64] = acc[ct][r] + bv;
        }
    }
}

// -------------------- launcher --------------------
extern "C" void kernel_launch(void* const* d_in, const int* in_sizes, int n_in,
                              void* d_out, int out_size, void* d_ws, size_t ws_size,
                              hipStream_t stream) {
    const float* x   = (const float*)d_in[0];
    const int*   ei  = (const int*)d_in[1];
    const float* W1  = (const float*)d_in[2];
    const float* b1  = (const float*)d_in[3];
    const float* Wmu = (const float*)d_in[4];
    const float* bmu = (const float*)d_in[5];
    const float* Wlv = (const float*)d_in[6];
    const float* blv = (const float*)d_in[7];
    float* out = (float*)d_out;

    const int N = in_sizes[0] / 128;
    const int E = in_sizes[1] / 2;
    const int* src = ei;
    const int* dst = ei + E;

    const int nchunk = 256;
    const int NB = (N + 255) >> 8;
    const int M = NB * nchunk;

    // workspace (~66 MB)
    char* ws = (char*)d_ws;
    size_t off = 0;
    float* dinv   = (float*)(ws + off); off = ws_align(off + (size_t)N * 4);
    int* cnt      = (int*)(ws + off);   off = ws_align(off + (size_t)N * 4);
    int* rp       = (int*)(ws + off);   off = ws_align(off + (size_t)(N + 1) * 4);
    int* bsum     = (int*)(ws + off);   off = ws_align(off + 1024 * 4);
    int* cntAB    = (int*)(ws + off);   off = ws_align(off + (size_t)(M + 64) * 4);
    int* baseAB   = (int*)(ws + off);   off = ws_align(off + (size_t)(M + 64) * 4);
    uint2* cedge  = (uint2*)(ws + off); off = ws_align(off + (size_t)E * 8);
    uint32_t* xb  = (uint32_t*)(ws + off); off = ws_align(off + (size_t)N * 256);  // x~ / G2
    uint8_t* F1   = (uint8_t*)(ws + off);  off = ws_align(off + (size_t)N * 256);  // agg1 -> h
    uint2* ebkt   = (uint2*)xb;  // aliases xb: dead before k_cvt writes xb

    const int b = 256;

    // ---- bucket-sorted CSR build: zero device-scope atomics ----
    k_bcount<<<nchunk, 256, 0, stream>>>(dst, cntAB, E, nchunk, NB);
    k_scan1<<<(M + 1023) / 1024, 256, 0, stream>>>(cntAB, baseAB, bsum, M);
    k_scan2<<<1, 256, 0, stream>>>(bsum, (M + 1023) / 1024);
    k_scan3<<<(M + 1 + b - 1) / b, b, 0, stream>>>(baseAB, bsum, M, E);   // baseAB[M] = E
    k_bscatter<<<nchunk, 256, 0, stream>>>(src, dst, baseAB, ebkt, E, nchunk, NB);
    k_bhist<<<NB, 256, 0, stream>>>(ebkt, baseAB, cnt, dinv, nchunk, N);
    k_scan1<<<(N + 1023) / 1024, 256, 0, stream>>>(cnt, rp, bsum, N);
    k_scan2<<<1, 256, 0, stream>>>(bsum, (N + 1023) / 1024);
    k_scan3<<<(N + 1 + b - 1) / b, b, 0, stream>>>(rp, bsum, N, E);       // rp[N] = E
    k_bfill<<<NB, 256, 0, stream>>>(ebkt, baseAB, rp, dinv, cedge, nchunk);

    // ---- layer 1 ----
    k_cvt<<<(N * 32 + b - 1) / b, b, 0, stream>>>(x, xb, N * 32);
    const int aggBlocks = (N + 3) / 4;
    k_agg<<<aggBlocks, 256, 0, stream>>>((const uint8_t*)xb, (uint32_t*)F1, rp, cedge, dinv, N);
    k_gemm1_mfma<<<(N + 63) / 64, 256, 0, stream>>>(F1, F1, W1, b1, N);

    // ---- layer 2 ----
    k_agg<<<aggBlocks, 256, 0, stream>>>(F1, (uint32_t*)xb, rp, cedge, dinv, N);
    k_gemm2_mfma<<<(N + 63) / 64, 256, 0, stream>>>((const uint8_t*)xb, out, Wmu, Wlv, bmu, blv, N);
}

// Round 9
// 240.181 us; speedup vs baseline: 12.2378x; 1.0232x over previous
//
#include <hip/hip_runtime.h>
#include <hip/hip_bf16.h>
#include <stdint.h>

static inline size_t ws_align(size_t x) { return (x + 255) & ~(size_t)255; }

typedef __attribute__((ext_vector_type(8))) short bf16x8;
typedef __attribute__((ext_vector_type(4))) float f32x4;

// RTNE f32 -> bf16 pair packed into uint32 (elem0 in low 16)
__device__ __forceinline__ uint32_t pack_bf16(float a, float b) {
    uint32_t ua = __float_as_uint(a), ub = __float_as_uint(b);
    ua = (ua + 0x7fffu + ((ua >> 16) & 1u)) >> 16;
    ub = (ub + 0x7fffu + ((ub >> 16) & 1u)) >> 16;
    return ua | (ub << 16);
}
__device__ __forceinline__ uint16_t cvt_bf16(float a) {
    uint32_t ua = __float_as_uint(a);
    return (uint16_t)((ua + 0x7fffu + ((ua >> 16) & 1u)) >> 16);
}
__device__ __forceinline__ float bf_lo(uint32_t v) { return __uint_as_float(v << 16); }
__device__ __forceinline__ float bf_hi(uint32_t v) { return __uint_as_float(v & 0xffff0000u); }

// 8 bf16 lanes of g, weight wt, into acc[8]
__device__ __forceinline__ void fma8(float* acc, uint4 g, float wt) {
    acc[0] = fmaf(bf_lo(g.x), wt, acc[0]); acc[1] = fmaf(bf_hi(g.x), wt, acc[1]);
    acc[2] = fmaf(bf_lo(g.y), wt, acc[2]); acc[3] = fmaf(bf_hi(g.y), wt, acc[3]);
    acc[4] = fmaf(bf_lo(g.z), wt, acc[4]); acc[5] = fmaf(bf_hi(g.z), wt, acc[5]);
    acc[6] = fmaf(bf_lo(g.w), wt, acc[6]); acc[7] = fmaf(bf_hi(g.w), wt, acc[7]);
}

// ==================== bucket sort (no device-scope atomics anywhere) ====================

// Phase A: per (chunk, bucket) edge counts. LDS atomics only.
__global__ __launch_bounds__(256) void k_bcount(const int* __restrict__ dst, int* __restrict__ cntAB,
                                                int E, int nchunk, int NB) {
    __shared__ int h[512];
    for (int t = threadIdx.x; t < NB; t += 256) h[t] = 0;
    __syncthreads();
    const int c = blockIdx.x;
    const int per = (E + nchunk - 1) / nchunk;
    const int e0 = c * per, e1 = (e0 + per < E) ? e0 + per : E;
    for (int e = e0 + threadIdx.x; e < e1; e += 256)
        atomicAdd(&h[dst[e] >> 8], 1);
    __syncthreads();
    for (int t = threadIdx.x; t < NB; t += 256) cntAB[t * nchunk + c] = h[t];
}

// Phase B: scatter (src,dst) into bucket-grouped ebkt via LDS bump allocators.
__global__ __launch_bounds__(256) void k_bscatter(const int* __restrict__ src, const int* __restrict__ dst,
                                                  const int* __restrict__ baseAB, uint2* __restrict__ ebkt,
                                                  int E, int nchunk, int NB) {
    __shared__ int bump[512];
    const int c = blockIdx.x;
    for (int t = threadIdx.x; t < NB; t += 256) bump[t] = baseAB[t * nchunk + c];
    __syncthreads();
    const int per = (E + nchunk - 1) / nchunk;
    const int e0 = c * per, e1 = (e0 + per < E) ? e0 + per : E;
    for (int e = e0 + threadIdx.x; e < e1; e += 256) {
        int d = dst[e], s = src[e];
        int pos = atomicAdd(&bump[d >> 8], 1);
        ebkt[pos] = make_uint2((uint32_t)s, (uint32_t)d);
    }
}

// Phase C1: per-bucket dst histogram + block-local exclusive scan -> rp, dinv directly.
__global__ __launch_bounds__(256) void k_bhist(const uint2* __restrict__ ebkt, const int* __restrict__ baseAB,
                                               float* __restrict__ dinv, int* __restrict__ rp,
                                               int nchunk, int N, int E) {
    __shared__ int h[256];
    __shared__ int sh[256];
    h[threadIdx.x] = 0;
    __syncthreads();
    const int b = blockIdx.x;
    const int e0 = baseAB[b * nchunk], e1 = baseAB[(b + 1) * nchunk];  // sentinel [NB*nchunk]=E
    for (int e = e0 + threadIdx.x; e < e1; e += 256)
        atomicAdd(&h[ebkt[e].y & 255], 1);
    __syncthreads();
    const int t = threadIdx.x;
    const int c = h[t];
    sh[t] = c;
    __syncthreads();
    for (int off = 1; off < 256; off <<= 1) {
        int x = (t >= off) ? sh[t - off] : 0;
        __syncthreads();
        sh[t] += x;
        __syncthreads();
    }
    int node = (b << 8) + t;
    if (node < N) {
        rp[node] = e0 + sh[t] - c;   // exclusive scan + bucket base
        dinv[node] = rsqrtf((float)(c + 1));
    }
    if (blockIdx.x == gridDim.x - 1 && t == 0) rp[N] = E;
}

// Phase C2: per-bucket placement via LDS fill counters -> cedge (src, weight).
__global__ __launch_bounds__(256) void k_bfill(const uint2* __restrict__ ebkt, const int* __restrict__ baseAB,
                                               const int* __restrict__ rp, const float* __restrict__ dinv,
                                               uint2* __restrict__ cedge, int nchunk) {
    __shared__ int fl[256];
    fl[threadIdx.x] = 0;
    __syncthreads();
    const int b = blockIdx.x;
    const int e0 = baseAB[b * nchunk], e1 = baseAB[(b + 1) * nchunk];
    for (int e = e0 + threadIdx.x; e < e1; e += 256) {
        uint2 sd = ebkt[e];
        int d = (int)sd.y;
        int posL = atomicAdd(&fl[d & 255], 1);
        cedge[rp[d] + posL] = make_uint2(sd.x, __float_as_uint(dinv[sd.x] * dinv[d]));
    }
}

// -------------------- exclusive scan (used for the M = NB*nchunk table only) --------------------
__global__ __launch_bounds__(256) void k_scan1(const int* __restrict__ cnt, int* __restrict__ rp,
                                               int* __restrict__ bsum, int N) {
    __shared__ int sh[256];
    int t = threadIdx.x;
    int base = blockIdx.x * 1024 + t * 4;
    int v[4];
#pragma unroll
    for (int i = 0; i < 4; i++) v[i] = (base + i < N) ? cnt[base + i] : 0;
    int s = v[0] + v[1] + v[2] + v[3];
    sh[t] = s;
    __syncthreads();
    for (int off = 1; off < 256; off <<= 1) {
        int x = (t >= off) ? sh[t - off] : 0;
        __syncthreads();
        sh[t] += x;
        __syncthreads();
    }
    int excl = sh[t] - s;
    if (t == 255) bsum[blockIdx.x] = sh[255];
    int run = excl;
#pragma unroll
    for (int i = 0; i < 4; i++) {
        if (base + i < N) rp[base + i] = run;
        run += v[i];
    }
}

__global__ __launch_bounds__(256) void k_scan2(int* __restrict__ bsum, int nb) {
    __shared__ int sh[256];
    int t = threadIdx.x;
    int v = (t < nb) ? bsum[t] : 0;
    sh[t] = v;
    __syncthreads();
    for (int off = 1; off < 256; off <<= 1) {
        int x = (t >= off) ? sh[t - off] : 0;
        __syncthreads();
        sh[t] += x;
        __syncthreads();
    }
    if (t < nb) bsum[t] = sh[t] - v;
}

__global__ void k_scan3(int* __restrict__ rp, const int* __restrict__ bsum, int N, int E) {
    int i = blockIdx.x * blockDim.x + threadIdx.x;
    if (i < N) rp[i] += bsum[i >> 10];
    if (i == N) rp[N] = E;  // sentinel
}

// -------------------- f32 -> packed bf16 convert --------------------
__global__ void k_cvt(const float* __restrict__ in, uint32_t* __restrict__ outp, int n4) {
    int idx = blockIdx.x * blockDim.x + threadIdx.x;
    if (idx >= n4) return;
    float4 v = ((const float4*)in)[idx];
    ((uint2*)outp)[idx] = make_uint2(pack_bf16(v.x, v.y), pack_bf16(v.z, v.w));
}

// -------------------- aggregation: 4-deep batched gather --------------------
// Wave = 1 node. Lane = (quarter q, col-oct j). Per batch: 4 cedge loads issued, then
// 4 independent 16-B feat gathers (invalid slots: weight 0 x row 0), then 32 FMAs.
// ~4 KB in flight per wave. Quarter-reduce shfl_xor(16,32); q0 writes the 256-B row.
__global__ __launch_bounds__(256) void k_agg(const uint8_t* __restrict__ featB,
                                             uint32_t* __restrict__ outB,
                                             const int* __restrict__ rp,
                                             const uint2* __restrict__ cedge,
                                             const float* __restrict__ dinv, int N) {
    int node = blockIdx.x * 4 + (threadIdx.x >> 6);
    if (node >= N) return;
    int lane = threadIdx.x & 63;
    int j = lane & 15;   // 16-B col-oct
    int q = lane >> 4;   // edge phase
    int beg = rp[node], end = rp[node + 1];
    float di = dinv[node];
    float w0 = (q == 0) ? di * di : 0.0f;
    const uint8_t* fb = featB + (size_t)j * 16;

    uint4 sv = *(const uint4*)(fb + (size_t)node * 256);
    float acc[8];
    acc[0] = bf_lo(sv.x) * w0; acc[1] = bf_hi(sv.x) * w0;
    acc[2] = bf_lo(sv.y) * w0; acc[3] = bf_hi(sv.y) * w0;
    acc[4] = bf_lo(sv.z) * w0; acc[5] = bf_hi(sv.z) * w0;
    acc[6] = bf_lo(sv.w) * w0; acc[7] = bf_hi(sv.w) * w0;

    for (int base = beg + q; base < end; base += 16) {
        uint2 e0 = cedge[base];
        uint2 e1 = make_uint2(0u, 0u), e2 = make_uint2(0u, 0u), e3 = make_uint2(0u, 0u);
        if (base + 4 < end)  e1 = cedge[base + 4];
        if (base + 8 < end)  e2 = cedge[base + 8];
        if (base + 12 < end) e3 = cedge[base + 12];
        uint4 g0 = *(const uint4*)(fb + (size_t)e0.x * 256);
        uint4 g1 = *(const uint4*)(fb + (size_t)e1.x * 256);
        uint4 g2 = *(const uint4*)(fb + (size_t)e2.x * 256);
        uint4 g3 = *(const uint4*)(fb + (size_t)e3.x * 256);
        fma8(acc, g0, __uint_as_float(e0.y));
        fma8(acc, g1, __uint_as_float(e1.y));
        fma8(acc, g2, __uint_as_float(e2.y));
        fma8(acc, g3, __uint_as_float(e3.y));
    }

#pragma unroll
    for (int k = 0; k < 8; k++) {
        acc[k] += __shfl_xor(acc[k], 16, 64);
        acc[k] += __shfl_xor(acc[k], 32, 64);
    }
    if (q == 0) {
        uint4 p = make_uint4(pack_bf16(acc[0], acc[1]), pack_bf16(acc[2], acc[3]),
                             pack_bf16(acc[4], acc[5]), pack_bf16(acc[6], acc[7]));
        *(uint4*)(outB + (size_t)node * 64 + j * 4) = p;
    }
}

// -------------------- MFMA GEMM1: C = bf16(relu(A @ W + b)), in-place over A --------------------
__global__ __launch_bounds__(256) void k_gemm1_mfma(
        const uint8_t* __restrict__ A, uint8_t* __restrict__ C,
        const float* __restrict__ W, const float* __restrict__ bias, int N) {
    __shared__ uint32_t Bt[128 * 68];  // B^T: [n][k-pairs], 272B row stride
    {
        int c = threadIdx.x & 127;
        for (int k2 = threadIdx.x >> 7; k2 < 64; k2 += 2)
            Bt[c * 68 + k2] = pack_bf16(W[(2 * k2) * 128 + c], W[(2 * k2 + 1) * 128 + c]);
    }
    __syncthreads();

    const int lane = threadIdx.x & 63;
    const int wv = threadIdx.x >> 6;
    const int rrow = lane & 15;
    const int g = lane >> 4;
    const int r0 = blockIdx.x * 64 + wv * 16;
    const int rl = r0 + rrow;
    const int rc = (rl < N) ? rl : (N - 1);

    bf16x8 a[4];
    const uint8_t* arow = A + (size_t)rc * 256 + g * 16;
#pragma unroll
    for (int kb = 0; kb < 4; kb++) a[kb] = *(const bf16x8*)(arow + kb * 64);

    f32x4 acc[8];
#pragma unroll
    for (int ct = 0; ct < 8; ct++) acc[ct] = (f32x4){0.f, 0.f, 0.f, 0.f};

    const char* btb = (const char*)Bt;
#pragma unroll
    for (int ct = 0; ct < 8; ct++) {
        const char* bp = btb + (ct * 16 + rrow) * 272 + g * 16;
#pragma unroll
        for (int kb = 0; kb < 4; kb++) {
            bf16x8 bfr = *(const bf16x8*)(bp + kb * 64);
            acc[ct] = __builtin_amdgcn_mfma_f32_16x16x32_bf16(a[kb], bfr, acc[ct], 0, 0, 0);
        }
    }

#pragma unroll
    for (int ct = 0; ct < 8; ct++) {
        const int col = ct * 16 + rrow;
        const float bv = bias[col];
#pragma unroll
        for (int r = 0; r < 4; r++) {
            int row = r0 + g * 4 + r;
            if (row < N) {
                float h = fmaxf(acc[ct][r] + bv, 0.f);
                *(uint16_t*)(C + (size_t)row * 256 + col * 2) = cvt_bf16(h);
            }
        }
    }
}

// -------------------- MFMA GEMM2: out = A @ [Wmu|Wlv] + [bmu|blv] (f32, split) --------------------
__global__ __launch_bounds__(256) void k_gemm2_mfma(
        const uint8_t* __restrict__ A, float* __restrict__ out,
        const float* __restrict__ Wmu, const float* __restrict__ Wlv,
        const float* __restrict__ bmu, const float* __restrict__ blv, int N) {
    __shared__ uint32_t Bt[128 * 68];
    {
        int c = threadIdx.x & 127;
        const float* Wc = (c < 64) ? (Wmu + c) : (Wlv + (c - 64));
        for (int k2 = threadIdx.x >> 7; k2 < 64; k2 += 2)
            Bt[c * 68 + k2] = pack_bf16(Wc[(2 * k2) * 64], Wc[(2 * k2 + 1) * 64]);
    }
    __syncthreads();

    const int lane = threadIdx.x & 63;
    const int wv = threadIdx.x >> 6;
    const int rrow = lane & 15;
    const int g = lane >> 4;
    const int r0 = blockIdx.x * 64 + wv * 16;
    const int rl = r0 + rrow;
    const int rc = (rl < N) ? rl : (N - 1);

    bf16x8 a[4];
    const uint8_t* arow = A + (size_t)rc * 256 + g * 16;
#pragma unroll
    for (int kb = 0; kb < 4; kb++) a[kb] = *(const bf16x8*)(arow + kb * 64);

    f32x4 acc[8];
#pragma unroll
    for (int ct = 0; ct < 8; ct++) acc[ct] = (f32x4){0.f, 0.f, 0.f, 0.f};

    const char* btb = (const char*)Bt;
#pragma unroll
    for (int ct = 0; ct < 8; ct++) {
        const char* bp = btb + (ct * 16 + rrow) * 272 + g * 16;
#pragma unroll
        for (int kb = 0; kb < 4; kb++) {
            bf16x8 bfr = *(const bf16x8*)(bp + kb * 64);
            acc[ct] = __builtin_amdgcn_mfma_f32_16x16x32_bf16(a[kb], bfr, acc[ct], 0, 0, 0);
        }
    }

#pragma unroll
    for (int ct = 0; ct < 8; ct++) {
        const int col = ct * 16 + rrow;
        const float bv = (col < 64) ? bmu[col] : blv[col - 64];
        float* obase = (col < 64) ? (out + col) : (out + (size_t)N * 64 + (col - 64));
#pragma unroll
        for (int r = 0; r < 4; r++) {
            int row = r0 + g * 4 + r;
            if (row < N) obase[(size_t)row * 64] = acc[ct][r] + bv;
        }
    }
}

// -------------------- launcher --------------------
extern "C" void kernel_launch(void* const* d_in, const int* in_sizes, int n_in,
                              void* d_out, int out_size, void* d_ws, size_t ws_size,
                              hipStream_t stream) {
    const float* x   = (const float*)d_in[0];
    const int*   ei  = (const int*)d_in[1];
    const float* W1  = (const float*)d_in[2];
    const float* b1  = (const float*)d_in[3];
    const float* Wmu = (const float*)d_in[4];
    const float* bmu = (const float*)d_in[5];
    const float* Wlv = (const float*)d_in[6];
    const float* blv = (const float*)d_in[7];
    float* out = (float*)d_out;

    const int N = in_sizes[0] / 128;
    const int E = in_sizes[1] / 2;
    const int* src = ei;
    const int* dst = ei + E;

    const int nchunk = 256;
    const int NB = (N + 255) >> 8;
    const int M = NB * nchunk;

    // workspace (~66 MB)
    char* ws = (char*)d_ws;
    size_t off = 0;
    float* dinv   = (float*)(ws + off); off = ws_align(off + (size_t)N * 4);
    int* rp       = (int*)(ws + off);   off = ws_align(off + (size_t)(N + 1) * 4);
    int* bsum     = (int*)(ws + off);   off = ws_align(off + 1024 * 4);
    int* cntAB    = (int*)(ws + off);   off = ws_align(off + (size_t)(M + 64) * 4);
    int* baseAB   = (int*)(ws + off);   off = ws_align(off + (size_t)(M + 64) * 4);
    uint2* cedge  = (uint2*)(ws + off); off = ws_align(off + (size_t)E * 8);
    uint32_t* xb  = (uint32_t*)(ws + off); off = ws_align(off + (size_t)N * 256);  // x~ / G2
    uint8_t* F1   = (uint8_t*)(ws + off);  off = ws_align(off + (size_t)N * 256);  // agg1 -> h
    uint2* ebkt   = (uint2*)xb;  // aliases xb: dead before k_cvt writes xb

    const int b = 256;

    // ---- bucket-sorted CSR build: zero device-scope atomics ----
    k_bcount<<<nchunk, 256, 0, stream>>>(dst, cntAB, E, nchunk, NB);
    k_scan1<<<(M + 1023) / 1024, 256, 0, stream>>>(cntAB, baseAB, bsum, M);
    k_scan2<<<1, 256, 0, stream>>>(bsum, (M + 1023) / 1024);
    k_scan3<<<(M + 1 + b - 1) / b, b, 0, stream>>>(baseAB, bsum, M, E);   // baseAB[M] = E
    k_bscatter<<<nchunk, 256, 0, stream>>>(src, dst, baseAB, ebkt, E, nchunk, NB);
    k_bhist<<<NB, 256, 0, stream>>>(ebkt, baseAB, dinv, rp, nchunk, N, E);
    k_bfill<<<NB, 256, 0, stream>>>(ebkt, baseAB, rp, dinv, cedge, nchunk);

    // ---- layer 1 ----
    k_cvt<<<(N * 32 + b - 1) / b, b, 0, stream>>>(x, xb, N * 32);
    const int aggBlocks = (N + 3) / 4;
    k_agg<<<aggBlocks, 256, 0, stream>>>((const uint8_t*)xb, (uint32_t*)F1, rp, cedge, dinv, N);
    k_gemm1_mfma<<<(N + 63) / 64, 256, 0, stream>>>(F1, F1, W1, b1, N);

    // ---- layer 2 ----
    k_agg<<<aggBlocks, 256, 0, stream>>>(F1, (uint32_t*)xb, rp, cedge, dinv, N);
    k_gemm2_mfma<<<(N + 63) / 64, 256, 0, stream>>>((const uint8_t*)xb, out, Wmu, Wlv, bmu, blv, N);
}

// Round 10
// 223.810 us; speedup vs baseline: 13.1329x; 1.0731x over previous
//
#include <hip/hip_runtime.h>
#include <hip/hip_bf16.h>
#include <stdint.h>

static inline size_t ws_align(size_t x) { return (x + 255) & ~(size_t)255; }

typedef __attribute__((ext_vector_type(8))) short bf16x8;
typedef __attribute__((ext_vector_type(4))) float f32x4;

// RTNE f32 -> bf16 pair packed into uint32 (elem0 in low 16)
__device__ __forceinline__ uint32_t pack_bf16(float a, float b) {
    uint32_t ua = __float_as_uint(a), ub = __float_as_uint(b);
    ua = (ua + 0x7fffu + ((ua >> 16) & 1u)) >> 16;
    ub = (ub + 0x7fffu + ((ub >> 16) & 1u)) >> 16;
    return ua | (ub << 16);
}
__device__ __forceinline__ uint16_t cvt_bf16(float a) {
    uint32_t ua = __float_as_uint(a);
    return (uint16_t)((ua + 0x7fffu + ((ua >> 16) & 1u)) >> 16);
}
__device__ __forceinline__ float bf_lo(uint32_t v) { return __uint_as_float(v << 16); }
__device__ __forceinline__ float bf_hi(uint32_t v) { return __uint_as_float(v & 0xffff0000u); }

__device__ __forceinline__ void fma8(float* acc, uint4 g, float wt) {
    acc[0] = fmaf(bf_lo(g.x), wt, acc[0]); acc[1] = fmaf(bf_hi(g.x), wt, acc[1]);
    acc[2] = fmaf(bf_lo(g.y), wt, acc[2]); acc[3] = fmaf(bf_hi(g.y), wt, acc[3]);
    acc[4] = fmaf(bf_lo(g.z), wt, acc[4]); acc[5] = fmaf(bf_hi(g.z), wt, acc[5]);
    acc[6] = fmaf(bf_lo(g.w), wt, acc[6]); acc[7] = fmaf(bf_hi(g.w), wt, acc[7]);
}

// ==================== fused prologue: bcount | W->Bt convert | x->bf16 convert ====================
// blocks [0, nchunk): per-chunk dst bucket histogram (LDS atomics).
// blocks [nchunk, nchunk+34): W1 -> BtG1 packed-bf16 image.
// blocks [nchunk+34, nchunk+68): [Wmu|Wlv] -> BtG2 image.
// blocks [nchunk+68, ...): x f32 -> xb packed bf16.
__global__ __launch_bounds__(256) void k_pre(const int* __restrict__ dst, int* __restrict__ cntAB,
                                             const float* __restrict__ x, uint32_t* __restrict__ xb,
                                             const float* __restrict__ W1,
                                             const float* __restrict__ Wmu, const float* __restrict__ Wlv,
                                             uint32_t* __restrict__ BtG1, uint32_t* __restrict__ BtG2,
                                             int E, int nchunk, int NB, int n4) {
    const int b = blockIdx.x;
    if (b < nchunk) {
        __shared__ int h[512];
        for (int t = threadIdx.x; t < NB; t += 256) h[t] = 0;
        __syncthreads();
        const int per = (E + nchunk - 1) / nchunk;
        const int e0 = b * per, e1 = (e0 + per < E) ? e0 + per : E;
        for (int e = e0 + threadIdx.x; e < e1; e += 256)
            atomicAdd(&h[dst[e] >> 8], 1);
        __syncthreads();
        for (int t = threadIdx.x; t < NB; t += 256) cntAB[t * nchunk + b] = h[t];
    } else if (b < nchunk + 34) {
        int t = (b - nchunk) * 256 + threadIdx.x;   // t < 8704 = 128*68
        int c = t / 68, k2 = t % 68;
        uint32_t v = 0;
        if (k2 < 64) v = pack_bf16(W1[(2 * k2) * 128 + c], W1[(2 * k2 + 1) * 128 + c]);
        BtG1[t] = v;
    } else if (b < nchunk + 68) {
        int t = (b - nchunk - 34) * 256 + threadIdx.x;
        int c = t / 68, k2 = t % 68;
        uint32_t v = 0;
        if (k2 < 64) {
            const float* Wc = (c < 64) ? (Wmu + c) : (Wlv + (c - 64));
            v = pack_bf16(Wc[(2 * k2) * 64], Wc[(2 * k2 + 1) * 64]);
        }
        BtG2[t] = v;
    } else {
        int idx = (b - nchunk - 68) * 256 + threadIdx.x;
        if (idx < n4) {
            float4 v = ((const float4*)x)[idx];
            ((uint2*)xb)[idx] = make_uint2(pack_bf16(v.x, v.y), pack_bf16(v.z, v.w));
        }
    }
}

// -------------------- exclusive scan (M = NB*nchunk table) --------------------
__global__ __launch_bounds__(256) void k_scan1(const int* __restrict__ cnt, int* __restrict__ rp,
                                               int* __restrict__ bsum, int N) {
    __shared__ int sh[256];
    int t = threadIdx.x;
    int base = blockIdx.x * 1024 + t * 4;
    int v[4];
#pragma unroll
    for (int i = 0; i < 4; i++) v[i] = (base + i < N) ? cnt[base + i] : 0;
    int s = v[0] + v[1] + v[2] + v[3];
    sh[t] = s;
    __syncthreads();
    for (int off = 1; off < 256; off <<= 1) {
        int x = (t >= off) ? sh[t - off] : 0;
        __syncthreads();
        sh[t] += x;
        __syncthreads();
    }
    int excl = sh[t] - s;
    if (t == 255) bsum[blockIdx.x] = sh[255];
    int run = excl;
#pragma unroll
    for (int i = 0; i < 4; i++) {
        if (base + i < N) rp[base + i] = run;
        run += v[i];
    }
}

__global__ __launch_bounds__(256) void k_scan2(int* __restrict__ bsum, int nb) {
    __shared__ int sh[256];
    int t = threadIdx.x;
    int v = (t < nb) ? bsum[t] : 0;
    sh[t] = v;
    __syncthreads();
    for (int off = 1; off < 256; off <<= 1) {
        int x = (t >= off) ? sh[t - off] : 0;
        __syncthreads();
        sh[t] += x;
        __syncthreads();
    }
    if (t < nb) bsum[t] = sh[t] - v;
}

__global__ void k_scan3(int* __restrict__ rp, const int* __restrict__ bsum, int N, int E) {
    int i = blockIdx.x * blockDim.x + threadIdx.x;
    if (i < N) rp[i] += bsum[i >> 10];
    if (i == N) rp[N] = E;  // sentinel
}

// -------------------- Phase B: scatter (src,dst) into bucket-grouped ebkt --------------------
__global__ __launch_bounds__(256) void k_bscatter(const int* __restrict__ src, const int* __restrict__ dst,
                                                  const int* __restrict__ baseAB, uint2* __restrict__ ebkt,
                                                  int E, int nchunk, int NB) {
    __shared__ int bump[512];
    const int c = blockIdx.x;
    for (int t = threadIdx.x; t < NB; t += 256) bump[t] = baseAB[t * nchunk + c];
    __syncthreads();
    const int per = (E + nchunk - 1) / nchunk;
    const int e0 = c * per, e1 = (e0 + per < E) ? e0 + per : E;
    for (int e = e0 + threadIdx.x; e < e1; e += 256) {
        int d = dst[e], s = src[e];
        int pos = atomicAdd(&bump[d >> 8], 1);
        ebkt[pos] = make_uint2((uint32_t)s, (uint32_t)d);
    }
}

// -------------------- Phase C (fused): histogram + scan -> rp,dinv; place -> csrc --------------------
// Pass 2 re-reads this bucket's ~32KB ebkt segment (L1/L2-hot). csrc is 4 B/edge; weights
// are recomputed in k_agg from dinv (L2-resident), removing the cross-bucket dinv race.
__global__ __launch_bounds__(256) void k_bbuild(const uint2* __restrict__ ebkt, const int* __restrict__ baseAB,
                                                float* __restrict__ dinv, int* __restrict__ rp,
                                                uint32_t* __restrict__ csrc, int nchunk, int N) {
    __shared__ int h[256];
    __shared__ int sh[256];
    __shared__ int rpd[256];
    __shared__ int fl[256];
    const int t = threadIdx.x;
    h[t] = 0;
    fl[t] = 0;
    __syncthreads();
    const int b = blockIdx.x;
    const int e0 = baseAB[b * nchunk], e1 = baseAB[(b + 1) * nchunk];  // sentinel [NB*nchunk]=E
    for (int e = e0 + t; e < e1; e += 256)
        atomicAdd(&h[ebkt[e].y & 255], 1);
    __syncthreads();
    const int c = h[t];
    sh[t] = c;
    __syncthreads();
    for (int off = 1; off < 256; off <<= 1) {
        int x = (t >= off) ? sh[t - off] : 0;
        __syncthreads();
        sh[t] += x;
        __syncthreads();
    }
    rpd[t] = e0 + sh[t] - c;  // this node's segment base
    int node = (b << 8) + t;
    if (node < N) {
        rp[node] = rpd[t];
        dinv[node] = rsqrtf((float)(c + 1));
    }
    if (node == N - 1 || t == 255) {
        if (node + 1 <= N && (node == N - 1)) rp[N] = e0 + sh[255];  // only true last block hits N-1
    }
    __syncthreads();
    for (int e = e0 + t; e < e1; e += 256) {
        uint2 sd = ebkt[e];
        int dl = (int)(sd.y & 255);
        int posL = atomicAdd(&fl[dl], 1);
        csrc[rpd[dl] + posL] = sd.x;
    }
}

// -------------------- aggregation: 4-deep batched gather, weights on the fly --------------------
__global__ __launch_bounds__(256) void k_agg(const uint8_t* __restrict__ featB,
                                             uint32_t* __restrict__ outB,
                                             const int* __restrict__ rp,
                                             const uint32_t* __restrict__ csrc,
                                             const float* __restrict__ dinv, int N) {
    int node = blockIdx.x * 4 + (threadIdx.x >> 6);
    if (node >= N) return;
    int lane = threadIdx.x & 63;
    int j = lane & 15;   // 16-B col-oct
    int q = lane >> 4;   // edge phase
    int beg = rp[node], end = rp[node + 1];
    float di = dinv[node];
    float w0 = (q == 0) ? di * di : 0.0f;
    const uint8_t* fb = featB + (size_t)j * 16;

    uint4 sv = *(const uint4*)(fb + (size_t)node * 256);
    float acc[8];
    acc[0] = bf_lo(sv.x) * w0; acc[1] = bf_hi(sv.x) * w0;
    acc[2] = bf_lo(sv.y) * w0; acc[3] = bf_hi(sv.y) * w0;
    acc[4] = bf_lo(sv.z) * w0; acc[5] = bf_hi(sv.z) * w0;
    acc[6] = bf_lo(sv.w) * w0; acc[7] = bf_hi(sv.w) * w0;

    for (int base = beg + q; base < end; base += 16) {
        bool v1 = base + 4 < end, v2 = base + 8 < end, v3 = base + 12 < end;
        uint32_t s0 = csrc[base];
        uint32_t s1 = v1 ? csrc[base + 4] : 0u;
        uint32_t s2 = v2 ? csrc[base + 8] : 0u;
        uint32_t s3 = v3 ? csrc[base + 12] : 0u;
        float wa = dinv[s0] * di;
        float wb = v1 ? dinv[s1] * di : 0.f;
        float wc = v2 ? dinv[s2] * di : 0.f;
        float wd = v3 ? dinv[s3] * di : 0.f;
        uint4 g0 = *(const uint4*)(fb + (size_t)s0 * 256);
        uint4 g1 = *(const uint4*)(fb + (size_t)s1 * 256);
        uint4 g2 = *(const uint4*)(fb + (size_t)s2 * 256);
        uint4 g3 = *(const uint4*)(fb + (size_t)s3 * 256);
        fma8(acc, g0, wa);
        fma8(acc, g1, wb);
        fma8(acc, g2, wc);
        fma8(acc, g3, wd);
    }

#pragma unroll
    for (int k = 0; k < 8; k++) {
        acc[k] += __shfl_xor(acc[k], 16, 64);
        acc[k] += __shfl_xor(acc[k], 32, 64);
    }
    if (q == 0) {
        uint4 p = make_uint4(pack_bf16(acc[0], acc[1]), pack_bf16(acc[2], acc[3]),
                             pack_bf16(acc[4], acc[5]), pack_bf16(acc[6], acc[7]));
        *(uint4*)(outB + (size_t)node * 64 + j * 4) = p;
    }
}

// -------------------- MFMA GEMM1: C = bf16(relu(A @ W + b)), Bt from global image --------------------
__global__ __launch_bounds__(256) void k_gemm1_mfma(
        const uint8_t* __restrict__ A, uint8_t* __restrict__ C,
        const uint32_t* __restrict__ BtG, const float* __restrict__ bias, int N) {
    __shared__ uint32_t Bt[128 * 68];
    for (int t = threadIdx.x; t < 128 * 68 / 4; t += 256)
        ((uint4*)Bt)[t] = ((const uint4*)BtG)[t];
    __syncthreads();

    const int lane = threadIdx.x & 63;
    const int wv = threadIdx.x >> 6;
    const int rrow = lane & 15;
    const int g = lane >> 4;
    const int r0 = blockIdx.x * 64 + wv * 16;
    const int rl = r0 + rrow;
    const int rc = (rl < N) ? rl : (N - 1);

    bf16x8 a[4];
    const uint8_t* arow = A + (size_t)rc * 256 + g * 16;
#pragma unroll
    for (int kb = 0; kb < 4; kb++) a[kb] = *(const bf16x8*)(arow + kb * 64);

    f32x4 acc[8];
#pragma unroll
    for (int ct = 0; ct < 8; ct++) acc[ct] = (f32x4){0.f, 0.f, 0.f, 0.f};

    const char* btb = (const char*)Bt;
#pragma unroll
    for (int ct = 0; ct < 8; ct++) {
        const char* bp = btb + (ct * 16 + rrow) * 272 + g * 16;
#pragma unroll
        for (int kb = 0; kb < 4; kb++) {
            bf16x8 bfr = *(const bf16x8*)(bp + kb * 64);
            acc[ct] = __builtin_amdgcn_mfma_f32_16x16x32_bf16(a[kb], bfr, acc[ct], 0, 0, 0);
        }
    }

#pragma unroll
    for (int ct = 0; ct < 8; ct++) {
        const int col = ct * 16 + rrow;
        const float bv = bias[col];
#pragma unroll
        for (int r = 0; r < 4; r++) {
            int row = r0 + g * 4 + r;
            if (row < N) {
                float h = fmaxf(acc[ct][r] + bv, 0.f);
                *(uint16_t*)(C + (size_t)row * 256 + col * 2) = cvt_bf16(h);
            }
        }
    }
}

// -------------------- MFMA GEMM2: out = A @ [Wmu|Wlv] + [bmu|blv] (f32, split) --------------------
__global__ __launch_bounds__(256) void k_gemm2_mfma(
        const uint8_t* __restrict__ A, float* __restrict__ out,
        const uint32_t* __restrict__ BtG,
        const float* __restrict__ bmu, const float* __restrict__ blv, int N) {
    __shared__ uint32_t Bt[128 * 68];
    for (int t = threadIdx.x; t < 128 * 68 / 4; t += 256)
        ((uint4*)Bt)[t] = ((const uint4*)BtG)[t];
    __syncthreads();

    const int lane = threadIdx.x & 63;
    const int wv = threadIdx.x >> 6;
    const int rrow = lane & 15;
    const int g = lane >> 4;
    const int r0 = blockIdx.x * 64 + wv * 16;
    const int rl = r0 + rrow;
    const int rc = (rl < N) ? rl : (N - 1);

    bf16x8 a[4];
    const uint8_t* arow = A + (size_t)rc * 256 + g * 16;
#pragma unroll
    for (int kb = 0; kb < 4; kb++) a[kb] = *(const bf16x8*)(arow + kb * 64);

    f32x4 acc[8];
#pragma unroll
    for (int ct = 0; ct < 8; ct++) acc[ct] = (f32x4){0.f, 0.f, 0.f, 0.f};

    const char* btb = (const char*)Bt;
#pragma unroll
    for (int ct = 0; ct < 8; ct++) {
        const char* bp = btb + (ct * 16 + rrow) * 272 + g * 16;
#pragma unroll
        for (int kb = 0; kb < 4; kb++) {
            bf16x8 bfr = *(const bf16x8*)(bp + kb * 64);
            acc[ct] = __builtin_amdgcn_mfma_f32_16x16x32_bf16(a[kb], bfr, acc[ct], 0, 0, 0);
        }
    }

#pragma unroll
    for (int ct = 0; ct < 8; ct++) {
        const int col = ct * 16 + rrow;
        const float bv = (col < 64) ? bmu[col] : blv[col - 64];
        float* obase = (col < 64) ? (out + col) : (out + (size_t)N * 64 + (col - 64));
#pragma unroll
        for (int r = 0; r < 4; r++) {
            int row = r0 + g * 4 + r;
            if (row < N) obase[(size_t)row * 64] = acc[ct][r] + bv;
        }
    }
}

// -------------------- launcher --------------------
extern "C" void kernel_launch(void* const* d_in, const int* in_sizes, int n_in,
                              void* d_out, int out_size, void* d_ws, size_t ws_size,
                              hipStream_t stream) {
    const float* x   = (const float*)d_in[0];
    const int*   ei  = (const int*)d_in[1];
    const float* W1  = (const float*)d_in[2];
    const float* b1  = (const float*)d_in[3];
    const float* Wmu = (const float*)d_in[4];
    const float* bmu = (const float*)d_in[5];
    const float* Wlv = (const float*)d_in[6];
    const float* blv = (const float*)d_in[7];
    float* out = (float*)d_out;

    const int N = in_sizes[0] / 128;
    const int E = in_sizes[1] / 2;
    const int* src = ei;
    const int* dst = ei + E;

    const int nchunk = 256;
    const int NB = (N + 255) >> 8;
    const int M = NB * nchunk;
    const int n4 = N * 32;

    // workspace (~60 MB)
    char* ws = (char*)d_ws;
    size_t off = 0;
    float* dinv    = (float*)(ws + off);    off = ws_align(off + (size_t)N * 4);
    int* rp        = (int*)(ws + off);      off = ws_align(off + (size_t)(N + 1) * 4);
    int* bsum      = (int*)(ws + off);      off = ws_align(off + 1024 * 4);
    int* cntAB     = (int*)(ws + off);      off = ws_align(off + (size_t)(M + 64) * 4);
    int* baseAB    = (int*)(ws + off);      off = ws_align(off + (size_t)(M + 64) * 4);
    uint32_t* BtG1 = (uint32_t*)(ws + off); off = ws_align(off + 128 * 68 * 4);
    uint32_t* BtG2 = (uint32_t*)(ws + off); off = ws_align(off + 128 * 68 * 4);
    uint32_t* csrc = (uint32_t*)(ws + off); off = ws_align(off + (size_t)E * 4);
    uint32_t* xb   = (uint32_t*)(ws + off); off = ws_align(off + (size_t)N * 256);  // x~ / G2
    uint8_t* F1    = (uint8_t*)(ws + off);  off = ws_align(off + (size_t)N * 256);  // agg1 -> h
    uint2* ebkt    = (uint2*)(ws + off);    off = ws_align(off + (size_t)E * 8);    // build-only

    const int b = 256;
    const int ncvt = (n4 + 255) / 256;

    // ---- fused prologue + bucket-sorted CSR build (no device-scope atomics) ----
    k_pre<<<nchunk + 68 + ncvt, 256, 0, stream>>>(dst, cntAB, x, xb, W1, Wmu, Wlv,
                                                  BtG1, BtG2, E, nchunk, NB, n4);
    k_scan1<<<(M + 1023) / 1024, 256, 0, stream>>>(cntAB, baseAB, bsum, M);
    k_scan2<<<1, 256, 0, stream>>>(bsum, (M + 1023) / 1024);
    k_scan3<<<(M + 1 + b - 1) / b, b, 0, stream>>>(baseAB, bsum, M, E);   // baseAB[M] = E
    k_bscatter<<<nchunk, 256, 0, stream>>>(src, dst, baseAB, ebkt, E, nchunk, NB);
    k_bbuild<<<NB, 256, 0, stream>>>(ebkt, baseAB, dinv, rp, csrc, nchunk, N);

    // ---- layer 1 ----
    const int aggBlocks = (N + 3) / 4;
    k_agg<<<aggBlocks, 256, 0, stream>>>((const uint8_t*)xb, (uint32_t*)F1, rp, csrc, dinv, N);
    k_gemm1_mfma<<<(N + 63) / 64, 256, 0, stream>>>(F1, F1, BtG1, b1, N);

    // ---- layer 2 ----
    k_agg<<<aggBlocks, 256, 0, stream>>>(F1, (uint32_t*)xb, rp, csrc, dinv, N);
    k_gemm2_mfma<<<(N + 63) / 64, 256, 0, stream>>>((const uint8_t*)xb, out, BtG2, bmu, blv, N);
}

// Round 11
// 221.713 us; speedup vs baseline: 13.2572x; 1.0095x over previous
//
#include <hip/hip_runtime.h>
#include <hip/hip_bf16.h>
#include <stdint.h>

static inline size_t ws_align(size_t x) { return (x + 255) & ~(size_t)255; }

typedef __attribute__((ext_vector_type(8))) short bf16x8;
typedef __attribute__((ext_vector_type(4))) float f32x4;

// RTNE f32 -> bf16 pair packed into uint32 (elem0 in low 16)
__device__ __forceinline__ uint32_t pack_bf16(float a, float b) {
    uint32_t ua = __float_as_uint(a), ub = __float_as_uint(b);
    ua = (ua + 0x7fffu + ((ua >> 16) & 1u)) >> 16;
    ub = (ub + 0x7fffu + ((ub >> 16) & 1u)) >> 16;
    return ua | (ub << 16);
}
__device__ __forceinline__ uint16_t cvt_bf16(float a) {
    uint32_t ua = __float_as_uint(a);
    return (uint16_t)((ua + 0x7fffu + ((ua >> 16) & 1u)) >> 16);
}
__device__ __forceinline__ float bf_lo(uint32_t v) { return __uint_as_float(v << 16); }
__device__ __forceinline__ float bf_hi(uint32_t v) { return __uint_as_float(v & 0xffff0000u); }

__device__ __forceinline__ void fma8(float* acc, uint4 g, float wt) {
    acc[0] = fmaf(bf_lo(g.x), wt, acc[0]); acc[1] = fmaf(bf_hi(g.x), wt, acc[1]);
    acc[2] = fmaf(bf_lo(g.y), wt, acc[2]); acc[3] = fmaf(bf_hi(g.y), wt, acc[3]);
    acc[4] = fmaf(bf_lo(g.z), wt, acc[4]); acc[5] = fmaf(bf_hi(g.z), wt, acc[5]);
    acc[6] = fmaf(bf_lo(g.w), wt, acc[6]); acc[7] = fmaf(bf_hi(g.w), wt, acc[7]);
}

// ==================== fused prologue: bcount | W->Bt convert | x->bf16 convert ====================
__global__ __launch_bounds__(256) void k_pre(const int* __restrict__ dst, int* __restrict__ cntAB,
                                             const float* __restrict__ x, uint32_t* __restrict__ xb,
                                             const float* __restrict__ W1,
                                             const float* __restrict__ Wmu, const float* __restrict__ Wlv,
                                             uint32_t* __restrict__ BtG1, uint32_t* __restrict__ BtG2,
                                             int E, int nchunk, int NB, int n4) {
    const int b = blockIdx.x;
    if (b < nchunk) {
        __shared__ int h[512];
        for (int t = threadIdx.x; t < NB; t += 256) h[t] = 0;
        __syncthreads();
        const int per = (E + nchunk - 1) / nchunk;
        const int e0 = b * per, e1 = (e0 + per < E) ? e0 + per : E;
        for (int e = e0 + threadIdx.x; e < e1; e += 256)
            atomicAdd(&h[dst[e] >> 8], 1);
        __syncthreads();
        for (int t = threadIdx.x; t < NB; t += 256) cntAB[t * nchunk + b] = h[t];
    } else if (b < nchunk + 34) {
        int t = (b - nchunk) * 256 + threadIdx.x;   // t < 8704 = 128*68
        int c = t / 68, k2 = t % 68;
        uint32_t v = 0;
        if (k2 < 64) v = pack_bf16(W1[(2 * k2) * 128 + c], W1[(2 * k2 + 1) * 128 + c]);
        BtG1[t] = v;
    } else if (b < nchunk + 68) {
        int t = (b - nchunk - 34) * 256 + threadIdx.x;
        int c = t / 68, k2 = t % 68;
        uint32_t v = 0;
        if (k2 < 64) {
            const float* Wc = (c < 64) ? (Wmu + c) : (Wlv + (c - 64));
            v = pack_bf16(Wc[(2 * k2) * 64], Wc[(2 * k2 + 1) * 64]);
        }
        BtG2[t] = v;
    } else {
        int idx = (b - nchunk - 68) * 256 + threadIdx.x;
        if (idx < n4) {
            float4 v = ((const float4*)x)[idx];
            ((uint2*)xb)[idx] = make_uint2(pack_bf16(v.x, v.y), pack_bf16(v.z, v.w));
        }
    }
}

// -------------------- scan1: per-1024-block exclusive scan + block totals --------------------
__global__ __launch_bounds__(256) void k_scan1(const int* __restrict__ cnt, int* __restrict__ rp,
                                               int* __restrict__ bsum, int N) {
    __shared__ int sh[256];
    int t = threadIdx.x;
    int base = blockIdx.x * 1024 + t * 4;
    int v[4];
#pragma unroll
    for (int i = 0; i < 4; i++) v[i] = (base + i < N) ? cnt[base + i] : 0;
    int s = v[0] + v[1] + v[2] + v[3];
    sh[t] = s;
    __syncthreads();
    for (int off = 1; off < 256; off <<= 1) {
        int x = (t >= off) ? sh[t - off] : 0;
        __syncthreads();
        sh[t] += x;
        __syncthreads();
    }
    int excl = sh[t] - s;
    if (t == 255) bsum[blockIdx.x] = sh[255];
    int run = excl;
#pragma unroll
    for (int i = 0; i < 4; i++) {
        if (base + i < N) rp[base + i] = run;
        run += v[i];
    }
}

// in-block exclusive scan of bsum[0..nb) into bexc[256] (nb <= 256)
__device__ __forceinline__ void scan_bsum_lds(const int* __restrict__ bsum, int nb, int* bexc) {
    const int t = threadIdx.x;
    int v = (t < nb) ? bsum[t] : 0;
    bexc[t] = v;
    __syncthreads();
    for (int off = 1; off < 256; off <<= 1) {
        int x = (t >= off) ? bexc[t - off] : 0;
        __syncthreads();
        bexc[t] += x;
        __syncthreads();
    }
    int excl = bexc[t] - v;
    __syncthreads();
    bexc[t] = excl;
    __syncthreads();
}

// -------------------- Phase B: scatter packed (srcl | dstLocal<<24) into bucket-grouped ebkt --------------------
__global__ __launch_bounds__(256) void k_bscatter(const int* __restrict__ src, const int* __restrict__ dst,
                                                  const int* __restrict__ baseAB, const int* __restrict__ bsum,
                                                  int nb, uint32_t* __restrict__ ebkt,
                                                  int E, int nchunk, int NB) {
    __shared__ int bump[512];
    __shared__ int bexc[256];
    scan_bsum_lds(bsum, nb, bexc);
    const int c = blockIdx.x;
    for (int t = threadIdx.x; t < NB; t += 256) {
        int idx = t * nchunk + c;
        bump[t] = baseAB[idx] + bexc[idx >> 10];
    }
    __syncthreads();
    const int per = (E + nchunk - 1) / nchunk;
    const int e0 = c * per, e1 = (e0 + per < E) ? e0 + per : E;
    for (int e = e0 + threadIdx.x; e < e1; e += 256) {
        int d = dst[e], s = src[e];
        int pos = atomicAdd(&bump[d >> 8], 1);
        ebkt[pos] = (uint32_t)s | ((uint32_t)(d & 255) << 24);
    }
}

// -------------------- Phase C (fused): histogram + scan -> rp,dinv; place -> csrc --------------------
__global__ __launch_bounds__(256) void k_bbuild(const uint32_t* __restrict__ ebkt,
                                                const int* __restrict__ baseAB, const int* __restrict__ bsum,
                                                int nb, float* __restrict__ dinv, int* __restrict__ rp,
                                                uint32_t* __restrict__ csrc, int nchunk, int N, int E, int NB) {
    __shared__ int h[256];
    __shared__ int sh[256];
    __shared__ int rpd[256];
    __shared__ int fl[256];
    __shared__ int bexc[256];
    scan_bsum_lds(bsum, nb, bexc);
    const int t = threadIdx.x;
    h[t] = 0;
    fl[t] = 0;
    __syncthreads();
    const int b = blockIdx.x;
    const int i0 = b * nchunk, i1 = (b + 1) * nchunk;
    const int e0 = baseAB[i0] + bexc[i0 >> 10];
    const int e1 = (i1 >= NB * nchunk) ? E : (baseAB[i1] + bexc[i1 >> 10]);
    for (int e = e0 + t; e < e1; e += 256)
        atomicAdd(&h[ebkt[e] >> 24], 1);
    __syncthreads();
    const int c = h[t];
    sh[t] = c;
    __syncthreads();
    for (int off = 1; off < 256; off <<= 1) {
        int x = (t >= off) ? sh[t - off] : 0;
        __syncthreads();
        sh[t] += x;
        __syncthreads();
    }
    rpd[t] = e0 + sh[t] - c;
    int node = (b << 8) + t;
    if (node < N) {
        rp[node] = rpd[t];
        dinv[node] = rsqrtf((float)(c + 1));
    }
    if (b == NB - 1 && t == 255) rp[N] = e0 + sh[255];  // = e1 = E
    __syncthreads();
    for (int e = e0 + t; e < e1; e += 256) {
        uint32_t sd = ebkt[e];
        int dl = (int)(sd >> 24);
        int posL = atomicAdd(&fl[dl], 1);
        csrc[rpd[dl] + posL] = sd & 0x00ffffffu;
    }
}

// -------------------- aggregation: 4-deep batched gather, weights on the fly --------------------
__global__ __launch_bounds__(256) void k_agg(const uint8_t* __restrict__ featB,
                                             uint32_t* __restrict__ outB,
                                             const int* __restrict__ rp,
                                             const uint32_t* __restrict__ csrc,
                                             const float* __restrict__ dinv, int N) {
    int node = blockIdx.x * 4 + (threadIdx.x >> 6);
    if (node >= N) return;
    int lane = threadIdx.x & 63;
    int j = lane & 15;   // 16-B col-oct
    int q = lane >> 4;   // edge phase
    int beg = rp[node], end = rp[node + 1];
    float di = dinv[node];
    float w0 = (q == 0) ? di * di : 0.0f;
    const uint8_t* fb = featB + (size_t)j * 16;

    uint4 sv = *(const uint4*)(fb + (size_t)node * 256);
    float acc[8];
    acc[0] = bf_lo(sv.x) * w0; acc[1] = bf_hi(sv.x) * w0;
    acc[2] = bf_lo(sv.y) * w0; acc[3] = bf_hi(sv.y) * w0;
    acc[4] = bf_lo(sv.z) * w0; acc[5] = bf_hi(sv.z) * w0;
    acc[6] = bf_lo(sv.w) * w0; acc[7] = bf_hi(sv.w) * w0;

    for (int base = beg + q; base < end; base += 16) {
        bool v1 = base + 4 < end, v2 = base + 8 < end, v3 = base + 12 < end;
        uint32_t s0 = csrc[base];
        uint32_t s1 = v1 ? csrc[base + 4] : 0u;
        uint32_t s2 = v2 ? csrc[base + 8] : 0u;
        uint32_t s3 = v3 ? csrc[base + 12] : 0u;
        float wa = dinv[s0] * di;
        float wb = v1 ? dinv[s1] * di : 0.f;
        float wc = v2 ? dinv[s2] * di : 0.f;
        float wd = v3 ? dinv[s3] * di : 0.f;
        uint4 g0 = *(const uint4*)(fb + (size_t)s0 * 256);
        uint4 g1 = *(const uint4*)(fb + (size_t)s1 * 256);
        uint4 g2 = *(const uint4*)(fb + (size_t)s2 * 256);
        uint4 g3 = *(const uint4*)(fb + (size_t)s3 * 256);
        fma8(acc, g0, wa);
        fma8(acc, g1, wb);
        fma8(acc, g2, wc);
        fma8(acc, g3, wd);
    }

#pragma unroll
    for (int k = 0; k < 8; k++) {
        acc[k] += __shfl_xor(acc[k], 16, 64);
        acc[k] += __shfl_xor(acc[k], 32, 64);
    }
    if (q == 0) {
        uint4 p = make_uint4(pack_bf16(acc[0], acc[1]), pack_bf16(acc[2], acc[3]),
                             pack_bf16(acc[4], acc[5]), pack_bf16(acc[6], acc[7]));
        *(uint4*)(outB + (size_t)node * 64 + j * 4) = p;
    }
}

// -------------------- MFMA GEMM1: C = bf16(relu(A @ W + b)), Bt from global image --------------------
__global__ __launch_bounds__(256) void k_gemm1_mfma(
        const uint8_t* __restrict__ A, uint8_t* __restrict__ C,
        const uint32_t* __restrict__ BtG, const float* __restrict__ bias, int N) {
    __shared__ uint32_t Bt[128 * 68];
    for (int t = threadIdx.x; t < 128 * 68 / 4; t += 256)
        ((uint4*)Bt)[t] = ((const uint4*)BtG)[t];
    __syncthreads();

    const int lane = threadIdx.x & 63;
    const int wv = threadIdx.x >> 6;
    const int rrow = lane & 15;
    const int g = lane >> 4;
    const int r0 = blockIdx.x * 64 + wv * 16;
    const int rl = r0 + rrow;
    const int rc = (rl < N) ? rl : (N - 1);

    bf16x8 a[4];
    const uint8_t* arow = A + (size_t)rc * 256 + g * 16;
#pragma unroll
    for (int kb = 0; kb < 4; kb++) a[kb] = *(const bf16x8*)(arow + kb * 64);

    f32x4 acc[8];
#pragma unroll
    for (int ct = 0; ct < 8; ct++) acc[ct] = (f32x4){0.f, 0.f, 0.f, 0.f};

    const char* btb = (const char*)Bt;
#pragma unroll
    for (int ct = 0; ct < 8; ct++) {
        const char* bp = btb + (ct * 16 + rrow) * 272 + g * 16;
#pragma unroll
        for (int kb = 0; kb < 4; kb++) {
            bf16x8 bfr = *(const bf16x8*)(bp + kb * 64);
            acc[ct] = __builtin_amdgcn_mfma_f32_16x16x32_bf16(a[kb], bfr, acc[ct], 0, 0, 0);
        }
    }

#pragma unroll
    for (int ct = 0; ct < 8; ct++) {
        const int col = ct * 16 + rrow;
        const float bv = bias[col];
#pragma unroll
        for (int r = 0; r < 4; r++) {
            int row = r0 + g * 4 + r;
            if (row < N) {
                float h = fmaxf(acc[ct][r] + bv, 0.f);
                *(uint16_t*)(C + (size_t)row * 256 + col * 2) = cvt_bf16(h);
            }
        }
    }
}

// -------------------- MFMA GEMM2: out = A @ [Wmu|Wlv] + [bmu|blv] (f32, split) --------------------
__global__ __launch_bounds__(256) void k_gemm2_mfma(
        const uint8_t* __restrict__ A, float* __restrict__ out,
        const uint32_t* __restrict__ BtG,
        const float* __restrict__ bmu, const float* __restrict__ blv, int N) {
    __shared__ uint32_t Bt[128 * 68];
    for (int t = threadIdx.x; t < 128 * 68 / 4; t += 256)
        ((uint4*)Bt)[t] = ((const uint4*)BtG)[t];
    __syncthreads();

    const int lane = threadIdx.x & 63;
    const int wv = threadIdx.x >> 6;
    const int rrow = lane & 15;
    const int g = lane >> 4;
    const int r0 = blockIdx.x * 64 + wv * 16;
    const int rl = r0 + rrow;
    const int rc = (rl < N) ? rl : (N - 1);

    bf16x8 a[4];
    const uint8_t* arow = A + (size_t)rc * 256 + g * 16;
#pragma unroll
    for (int kb = 0; kb < 4; kb++) a[kb] = *(const bf16x8*)(arow + kb * 64);

    f32x4 acc[8];
#pragma unroll
    for (int ct = 0; ct < 8; ct++) acc[ct] = (f32x4){0.f, 0.f, 0.f, 0.f};

    const char* btb = (const char*)Bt;
#pragma unroll
    for (int ct = 0; ct < 8; ct++) {
        const char* bp = btb + (ct * 16 + rrow) * 272 + g * 16;
#pragma unroll
        for (int kb = 0; kb < 4; kb++) {
            bf16x8 bfr = *(const bf16x8*)(bp + kb * 64);
            acc[ct] = __builtin_amdgcn_mfma_f32_16x16x32_bf16(a[kb], bfr, acc[ct], 0, 0, 0);
        }
    }

#pragma unroll
    for (int ct = 0; ct < 8; ct++) {
        const int col = ct * 16 + rrow;
        const float bv = (col < 64) ? bmu[col] : blv[col - 64];
        float* obase = (col < 64) ? (out + col) : (out + (size_t)N * 64 + (col - 64));
#pragma unroll
        for (int r = 0; r < 4; r++) {
            int row = r0 + g * 4 + r;
            if (row < N) obase[(size_t)row * 64] = acc[ct][r] + bv;
        }
    }
}

// -------------------- launcher --------------------
extern "C" void kernel_launch(void* const* d_in, const int* in_sizes, int n_in,
                              void* d_out, int out_size, void* d_ws, size_t ws_size,
                              hipStream_t stream) {
    const float* x   = (const float*)d_in[0];
    const int*   ei  = (const int*)d_in[1];
    const float* W1  = (const float*)d_in[2];
    const float* b1  = (const float*)d_in[3];
    const float* Wmu = (const float*)d_in[4];
    const float* bmu = (const float*)d_in[5];
    const float* Wlv = (const float*)d_in[6];
    const float* blv = (const float*)d_in[7];
    float* out = (float*)d_out;

    const int N = in_sizes[0] / 128;
    const int E = in_sizes[1] / 2;
    const int* src = ei;
    const int* dst = ei + E;

    const int nchunk = 256;
    const int NB = (N + 255) >> 8;
    const int M = NB * nchunk;
    const int n4 = N * 32;
    const int nscan = (M + 1023) / 1024;   // <= 256 required by scan_bsum_lds (true for N <= ~260k)

    // workspace (~55 MB)
    char* ws = (char*)d_ws;
    size_t off = 0;
    float* dinv    = (float*)(ws + off);    off = ws_align(off + (size_t)N * 4);
    int* rp        = (int*)(ws + off);      off = ws_align(off + (size_t)(N + 1) * 4);
    int* bsum      = (int*)(ws + off);      off = ws_align(off + 1024 * 4);
    int* cntAB     = (int*)(ws + off);      off = ws_align(off + (size_t)(M + 64) * 4);
    int* baseAB    = (int*)(ws + off);      off = ws_align(off + (size_t)(M + 64) * 4);
    uint32_t* BtG1 = (uint32_t*)(ws + off); off = ws_align(off + 128 * 68 * 4);
    uint32_t* BtG2 = (uint32_t*)(ws + off); off = ws_align(off + 128 * 68 * 4);
    uint32_t* csrc = (uint32_t*)(ws + off); off = ws_align(off + (size_t)E * 4);
    uint32_t* xb   = (uint32_t*)(ws + off); off = ws_align(off + (size_t)N * 256);  // x~ / G2
    uint8_t* F1    = (uint8_t*)(ws + off);  off = ws_align(off + (size_t)N * 256);  // agg1 -> h
    uint32_t* ebkt = (uint32_t*)(ws + off); off = ws_align(off + (size_t)E * 4);    // build-only

    const int ncvt = (n4 + 255) / 256;

    // ---- fused prologue + bucket-sorted CSR build (no device-scope atomics) ----
    k_pre<<<nchunk + 68 + ncvt, 256, 0, stream>>>(dst, cntAB, x, xb, W1, Wmu, Wlv,
                                                  BtG1, BtG2, E, nchunk, NB, n4);
    k_scan1<<<nscan, 256, 0, stream>>>(cntAB, baseAB, bsum, M);
    k_bscatter<<<nchunk, 256, 0, stream>>>(src, dst, baseAB, bsum, nscan, ebkt, E, nchunk, NB);
    k_bbuild<<<NB, 256, 0, stream>>>(ebkt, baseAB, bsum, nscan, dinv, rp, csrc, nchunk, N, E, NB);

    // ---- layer 1 ----
    const int aggBlocks = (N + 3) / 4;
    k_agg<<<aggBlocks, 256, 0, stream>>>((const uint8_t*)xb, (uint32_t*)F1, rp, csrc, dinv, N);
    k_gemm1_mfma<<<(N + 63) / 64, 256, 0, stream>>>(F1, F1, BtG1, b1, N);

    // ---- layer 2 ----
    k_agg<<<aggBlocks, 256, 0, stream>>>(F1, (uint32_t*)xb, rp, csrc, dinv, N);
    k_gemm2_mfma<<<(N + 63) / 64, 256, 0, stream>>>((const uint8_t*)xb, out, BtG2, bmu, blv, N);
}